// Round 1
// baseline (680.557 us; speedup 1.0000x reference)
//
#include <hip/hip_runtime.h>
#include <math.h>

#define NN 50000
#define NE 800000
#define NEP (NE + NN)   // edges incl self-loops
#define FIN 64
#define NH1 64
#define NH2 64
#define NHEADS 4
#define NOUT 32
#define NGRAPH 500

// ---------------- CSR construction ----------------

__global__ void k_count(const int* __restrict__ dst, int* __restrict__ cnt) {
    int e = blockIdx.x * blockDim.x + threadIdx.x;
    if (e < NE) atomicAdd(&cnt[dst[e]], 1);
}

// exclusive scan of (cnt[i]+1) -> row_ptr, single block of 1024 threads
__global__ void k_scan(const int* __restrict__ cnt, int* __restrict__ row_ptr) {
    __shared__ int buf[1024];
    __shared__ int carry;
    int tid = threadIdx.x;
    if (tid == 0) carry = 0;
    __syncthreads();
    for (int base = 0; base < NN; base += 1024) {
        int i = base + tid;
        int v = (i < NN) ? (cnt[i] + 1) : 0;
        buf[tid] = v;
        __syncthreads();
        for (int off = 1; off < 1024; off <<= 1) {
            int t = (tid >= off) ? buf[tid - off] : 0;
            __syncthreads();
            buf[tid] += t;
            __syncthreads();
        }
        int incl = buf[tid];
        if (i < NN) row_ptr[i] = carry + incl - v;
        __syncthreads();
        if (tid == 1023) carry += incl;
        __syncthreads();
    }
    if (tid == 0) row_ptr[NN] = carry;
}

__global__ void k_fill(const int* __restrict__ src, const int* __restrict__ dst,
                       const int* __restrict__ row_ptr, int* __restrict__ fill,
                       int* __restrict__ col) {
    int idx = blockIdx.x * blockDim.x + threadIdx.x;
    if (idx < NE) {
        int d = dst[idx];
        int p = row_ptr[d] + atomicAdd(&fill[d], 1);
        col[p] = src[idx];
    } else if (idx < NEP) {
        int i = idx - NE;
        int p = row_ptr[i] + atomicAdd(&fill[i], 1);
        col[p] = i;   // self loop
    }
}

__global__ void k_dinv(const int* __restrict__ cnt, float* __restrict__ dinv) {
    int i = blockIdx.x * blockDim.x + threadIdx.x;
    if (i < NN) dinv[i] = rsqrtf((float)(cnt[i] + 1));
}

// ---------------- GEMMs ----------------

// C[n x 64] = A[n x 64] @ B[64 x 64]; block=256, 64 rows per block
__global__ __launch_bounds__(256) void k_gemm64(const float* __restrict__ A,
                                                const float* __restrict__ B,
                                                float* __restrict__ C, int n) {
    __shared__ float Bs[64 * 64];
    int tid = threadIdx.x;
    for (int i = tid; i < 64 * 64; i += 256) Bs[i] = B[i];
    __syncthreads();
    int col = tid & 63;
    int rb = blockIdx.x * 64 + (tid >> 6) * 16;
    for (int r = 0; r < 16; ++r) {
        int row = rb + r;
        if (row >= n) return;
        const float* a = A + (size_t)row * 64;
        float acc = 0.f;
#pragma unroll
        for (int k = 0; k < 64; ++k) acc += a[k] * Bs[k * 64 + col];
        C[(size_t)row * 64 + col] = acc;
    }
}

// C[n x 256] = A[n x 64] @ B[64 x 256]; block=256, 16 rows per block
__global__ __launch_bounds__(256) void k_gemm256(const float* __restrict__ A,
                                                 const float* __restrict__ B,
                                                 float* __restrict__ C, int n) {
    __shared__ float Bs[64 * 256];  // 64 KB
    int tid = threadIdx.x;
    for (int i = tid; i < 64 * 256; i += 256) Bs[i] = B[i];
    __syncthreads();
    int col0 = tid & 63;
    int rb = blockIdx.x * 16 + (tid >> 6) * 4;
    for (int r = 0; r < 4; ++r) {
        int row = rb + r;
        if (row >= n) return;
        const float* a = A + (size_t)row * 64;
        float acc0 = 0.f, acc1 = 0.f, acc2 = 0.f, acc3 = 0.f;
#pragma unroll
        for (int k = 0; k < 64; ++k) {
            float av = a[k];
            acc0 += av * Bs[k * 256 + 0 * 64 + col0];
            acc1 += av * Bs[k * 256 + 1 * 64 + col0];
            acc2 += av * Bs[k * 256 + 2 * 64 + col0];
            acc3 += av * Bs[k * 256 + 3 * 64 + col0];
        }
        float* c = C + (size_t)row * 256;
        c[0 * 64 + col0] = acc0;
        c[1 * 64 + col0] = acc1;
        c[2 * 64 + col0] = acc2;
        c[3 * 64 + col0] = acc3;
    }
}

// ---------------- GCN aggregation: one wave per node, lane = feature ----------------

__global__ __launch_bounds__(256) void k_gcn_agg(const float* __restrict__ hx,
                                                 const int* __restrict__ row_ptr,
                                                 const int* __restrict__ col,
                                                 const float* __restrict__ dinv,
                                                 const float* __restrict__ bias,
                                                 float* __restrict__ h) {
    int wid = (blockIdx.x * blockDim.x + threadIdx.x) >> 6;
    int lane = threadIdx.x & 63;
    if (wid >= NN) return;
    int s0 = row_ptr[wid], s1 = row_ptr[wid + 1];
    float di = dinv[wid];
    float acc = 0.f;
    for (int k = s0; k < s1; ++k) {
        int s = col[k];
        float w = dinv[s] * di;
        acc += w * hx[(size_t)s * 64 + lane];
    }
    float v = acc + bias[lane];
    h[(size_t)wid * 64 + lane] = v > 0.f ? v : 0.f;
}

// ---------------- per-node attention logits a_s, a_d ----------------

__global__ __launch_bounds__(256) void k_att(const float* __restrict__ g,
                                             const float* __restrict__ att_src,
                                             const float* __restrict__ att_dst,
                                             float* __restrict__ a_s,
                                             float* __restrict__ a_d) {
    int wid = (blockIdx.x * blockDim.x + threadIdx.x) >> 6;
    int lane = threadIdx.x & 63;
    if (wid >= NN) return;
    const float* grow = g + (size_t)wid * 256;
#pragma unroll
    for (int hh = 0; hh < 4; ++hh) {
        float gv = grow[hh * 64 + lane];
        float vs = gv * att_src[hh * 64 + lane];
        float vd = gv * att_dst[hh * 64 + lane];
        for (int off = 32; off; off >>= 1) {
            vs += __shfl_xor(vs, off);
            vd += __shfl_xor(vd, off);
        }
        if (lane == 0) {
            a_s[wid * 4 + hh] = vs;
            a_d[wid * 4 + hh] = vd;
        }
    }
}

// ---------------- GAT: segment softmax + weighted aggregation + fused pooling ----------------

__device__ __forceinline__ float lrelu(float x) { return x > 0.f ? x : 0.2f * x; }

__global__ __launch_bounds__(256) void k_gat(const float* __restrict__ g,
                                             const float* __restrict__ a_s,
                                             const float* __restrict__ a_d,
                                             const int* __restrict__ row_ptr,
                                             const int* __restrict__ col,
                                             const float* __restrict__ gat_b,
                                             const int* __restrict__ batch,
                                             float* __restrict__ pool,
                                             float* __restrict__ cnt_g) {
    int wid = (blockIdx.x * blockDim.x + threadIdx.x) >> 6;
    int lane = threadIdx.x & 63;
    if (wid >= NN) return;
    int s0 = row_ptr[wid], s1 = row_ptr[wid + 1];
    float ad0 = a_d[wid * 4 + 0], ad1 = a_d[wid * 4 + 1];
    float ad2 = a_d[wid * 4 + 2], ad3 = a_d[wid * 4 + 3];

    // pass 1: per-head max over incoming edges
    float m0 = -1e30f, m1 = -1e30f, m2 = -1e30f, m3 = -1e30f;
    for (int k = s0 + lane; k < s1; k += 64) {
        int s = col[k];
        m0 = fmaxf(m0, lrelu(a_s[s * 4 + 0] + ad0));
        m1 = fmaxf(m1, lrelu(a_s[s * 4 + 1] + ad1));
        m2 = fmaxf(m2, lrelu(a_s[s * 4 + 2] + ad2));
        m3 = fmaxf(m3, lrelu(a_s[s * 4 + 3] + ad3));
    }
    for (int off = 32; off; off >>= 1) {
        m0 = fmaxf(m0, __shfl_xor(m0, off));
        m1 = fmaxf(m1, __shfl_xor(m1, off));
        m2 = fmaxf(m2, __shfl_xor(m2, off));
        m3 = fmaxf(m3, __shfl_xor(m3, off));
    }

    // pass 2: per-head sum of exp
    float t0 = 0.f, t1 = 0.f, t2 = 0.f, t3 = 0.f;
    for (int k = s0 + lane; k < s1; k += 64) {
        int s = col[k];
        t0 += __expf(lrelu(a_s[s * 4 + 0] + ad0) - m0);
        t1 += __expf(lrelu(a_s[s * 4 + 1] + ad1) - m1);
        t2 += __expf(lrelu(a_s[s * 4 + 2] + ad2) - m2);
        t3 += __expf(lrelu(a_s[s * 4 + 3] + ad3) - m3);
    }
    for (int off = 32; off; off >>= 1) {
        t0 += __shfl_xor(t0, off);
        t1 += __shfl_xor(t1, off);
        t2 += __shfl_xor(t2, off);
        t3 += __shfl_xor(t3, off);
    }
    float r0 = 1.f / t0, r1 = 1.f / t1, r2 = 1.f / t2, r3 = 1.f / t3;

    // pass 3: weighted aggregation, lane = feature within each head
    float acc0 = 0.f, acc1 = 0.f, acc2 = 0.f, acc3 = 0.f;
    for (int k = s0; k < s1; ++k) {
        int s = col[k];
        float w0 = __expf(lrelu(a_s[s * 4 + 0] + ad0) - m0) * r0;
        float w1 = __expf(lrelu(a_s[s * 4 + 1] + ad1) - m1) * r1;
        float w2 = __expf(lrelu(a_s[s * 4 + 2] + ad2) - m2) * r2;
        float w3 = __expf(lrelu(a_s[s * 4 + 3] + ad3) - m3) * r3;
        const float* gr = g + (size_t)s * 256;
        acc0 += w0 * gr[0 * 64 + lane];
        acc1 += w1 * gr[1 * 64 + lane];
        acc2 += w2 * gr[2 * 64 + lane];
        acc3 += w3 * gr[3 * 64 + lane];
    }

    float z0 = acc0 + gat_b[0 * 64 + lane]; z0 = z0 > 0.f ? z0 : 0.f;
    float z1 = acc1 + gat_b[1 * 64 + lane]; z1 = z1 > 0.f ? z1 : 0.f;
    float z2 = acc2 + gat_b[2 * 64 + lane]; z2 = z2 > 0.f ? z2 : 0.f;
    float z3 = acc3 + gat_b[3 * 64 + lane]; z3 = z3 > 0.f ? z3 : 0.f;

    int b = batch[wid];
    float* p = pool + (size_t)b * 256;
    atomicAdd(&p[0 * 64 + lane], z0);
    atomicAdd(&p[1 * 64 + lane], z1);
    atomicAdd(&p[2 * 64 + lane], z2);
    atomicAdd(&p[3 * 64 + lane], z3);
    if (lane == 0) atomicAdd(&cnt_g[b], 1.0f);
}

// ---------------- output projection ----------------

__global__ void k_out(const float* __restrict__ pool, const float* __restrict__ cnt_g,
                      const float* __restrict__ W, const float* __restrict__ b,
                      float* __restrict__ out) {
    int idx = blockIdx.x * blockDim.x + threadIdx.x;
    if (idx >= NGRAPH * NOUT) return;
    int gg = idx >> 5, o = idx & 31;
    float c = cnt_g[gg];
    c = c > 1.f ? c : 1.f;
    float rinv = 1.f / c;
    const float* p = pool + (size_t)gg * 256;
    float acc = 0.f;
#pragma unroll 8
    for (int f = 0; f < 256; ++f) acc += p[f] * W[f * 32 + o];
    out[idx] = acc * rinv + b[o];
}

// ---------------- launch ----------------

extern "C" void kernel_launch(void* const* d_in, const int* in_sizes, int n_in,
                              void* d_out, int out_size, void* d_ws, size_t ws_size,
                              hipStream_t stream) {
    const float* x       = (const float*)d_in[0];
    const int*   eidx    = (const int*)d_in[1];
    const int*   batch   = (const int*)d_in[2];
    const float* gcn_W   = (const float*)d_in[3];
    const float* gcn_b   = (const float*)d_in[4];
    const float* gat_W   = (const float*)d_in[5];
    const float* att_src = (const float*)d_in[6];
    const float* att_dst = (const float*)d_in[7];
    const float* gat_b   = (const float*)d_in[8];
    const float* out_W   = (const float*)d_in[9];
    const float* out_b   = (const float*)d_in[10];
    float* out = (float*)d_out;

    const int* src = eidx;        // edge_index[0]
    const int* dst = eidx + NE;   // edge_index[1]

    // workspace carve-up (256B aligned)
    size_t off = 0;
    auto carve = [&](size_t bytes) -> char* {
        char* p = (char*)d_ws + off;
        off += (bytes + 255) & ~(size_t)255;
        return p;
    };
    int*   cnt     = (int*)carve(NN * sizeof(int));
    int*   fill    = (int*)carve(NN * sizeof(int));
    int*   row_ptr = (int*)carve((NN + 1) * sizeof(int));
    int*   colb    = (int*)carve((size_t)NEP * sizeof(int));
    float* dinv    = (float*)carve(NN * sizeof(float));
    float* hx      = (float*)carve((size_t)NN * 64 * sizeof(float));
    float* h       = (float*)carve((size_t)NN * 64 * sizeof(float));
    float* g       = (float*)carve((size_t)NN * 256 * sizeof(float));
    float* a_s     = (float*)carve((size_t)NN * 4 * sizeof(float));
    float* a_d     = (float*)carve((size_t)NN * 4 * sizeof(float));
    float* pool    = (float*)carve((size_t)NGRAPH * 256 * sizeof(float));
    float* cnt_g   = (float*)carve(NGRAPH * sizeof(float));

    hipMemsetAsync(cnt, 0, NN * sizeof(int), stream);
    hipMemsetAsync(fill, 0, NN * sizeof(int), stream);
    hipMemsetAsync(pool, 0, (size_t)NGRAPH * 256 * sizeof(float), stream);
    hipMemsetAsync(cnt_g, 0, NGRAPH * sizeof(float), stream);

    // CSR build
    k_count<<<(NE + 255) / 256, 256, 0, stream>>>(dst, cnt);
    k_scan<<<1, 1024, 0, stream>>>(cnt, row_ptr);
    k_fill<<<(NEP + 255) / 256, 256, 0, stream>>>(src, dst, row_ptr, fill, colb);
    k_dinv<<<(NN + 255) / 256, 256, 0, stream>>>(cnt, dinv);

    // GCN
    k_gemm64<<<(NN + 63) / 64, 256, 0, stream>>>(x, gcn_W, hx, NN);
    k_gcn_agg<<<(NN * 64 + 255) / 256, 256, 0, stream>>>(hx, row_ptr, colb, dinv, gcn_b, h);

    // GAT
    k_gemm256<<<(NN + 15) / 16, 256, 0, stream>>>(h, gat_W, g, NN);
    k_att<<<(NN * 64 + 255) / 256, 256, 0, stream>>>(g, att_src, att_dst, a_s, a_d);
    k_gat<<<(NN * 64 + 255) / 256, 256, 0, stream>>>(g, a_s, a_d, row_ptr, colb, gat_b,
                                                     batch, pool, cnt_g);

    // output projection
    k_out<<<(NGRAPH * NOUT + 255) / 256, 256, 0, stream>>>(pool, cnt_g, out_W, out_b, out);
}

// Round 2
// 524.148 us; speedup vs baseline: 1.2984x; 1.2984x over previous
//
#include <hip/hip_runtime.h>
#include <math.h>

#define NN 50000
#define NE 800000
#define NEP (NE + NN)   // edges incl self-loops
#define NGRAPH 500
#define NOUT 32

// ---------------- CSR construction ----------------

__global__ void k_count(const int* __restrict__ dst, int* __restrict__ cnt) {
    int e = blockIdx.x * blockDim.x + threadIdx.x;
    if (e < NE) atomicAdd(&cnt[dst[e]], 1);
}

// pass 1: per-block sums of (cnt[i]+1)
__global__ __launch_bounds__(256) void k_scan1(const int* __restrict__ cnt, int* __restrict__ bsum) {
    __shared__ int buf[256];
    int i = blockIdx.x * 256 + threadIdx.x;
    int v = (i < NN) ? (cnt[i] + 1) : 0;
    buf[threadIdx.x] = v;
    __syncthreads();
    for (int off = 128; off; off >>= 1) {
        if (threadIdx.x < off) buf[threadIdx.x] += buf[threadIdx.x + off];
        __syncthreads();
    }
    if (threadIdx.x == 0) bsum[blockIdx.x] = buf[0];
}

// pass 2: exclusive scan of block sums (nblk <= 256), single block
__global__ __launch_bounds__(256) void k_scan2(int* __restrict__ bsum, int nblk) {
    __shared__ int buf[256];
    int tid = threadIdx.x;
    int v = (tid < nblk) ? bsum[tid] : 0;
    buf[tid] = v;
    __syncthreads();
    for (int off = 1; off < 256; off <<= 1) {
        int t = (tid >= off) ? buf[tid - off] : 0;
        __syncthreads();
        buf[tid] += t;
        __syncthreads();
    }
    if (tid < nblk) bsum[tid] = buf[tid] - v;  // exclusive
}

// pass 3: intra-block exclusive scan + block offset -> row_ptr
__global__ __launch_bounds__(256) void k_scan3(const int* __restrict__ cnt,
                                               const int* __restrict__ bsum,
                                               int* __restrict__ row_ptr) {
    __shared__ int buf[256];
    int tid = threadIdx.x;
    int i = blockIdx.x * 256 + tid;
    int v = (i < NN) ? (cnt[i] + 1) : 0;
    buf[tid] = v;
    __syncthreads();
    for (int off = 1; off < 256; off <<= 1) {
        int t = (tid >= off) ? buf[tid - off] : 0;
        __syncthreads();
        buf[tid] += t;
        __syncthreads();
    }
    if (i < NN) row_ptr[i] = bsum[blockIdx.x] + buf[tid] - v;
    if (i == NN - 1) row_ptr[NN] = bsum[blockIdx.x] + buf[tid];
}

__global__ void k_fill(const int* __restrict__ src, const int* __restrict__ dst,
                       const int* __restrict__ row_ptr, int* __restrict__ fill,
                       int* __restrict__ col) {
    int idx = blockIdx.x * blockDim.x + threadIdx.x;
    if (idx < NE) {
        int d = dst[idx];
        int p = row_ptr[d] + atomicAdd(&fill[d], 1);
        col[p] = src[idx];
    } else if (idx < NEP) {
        int i = idx - NE;
        int p = row_ptr[i] + atomicAdd(&fill[i], 1);
        col[p] = i;   // self loop
    }
}

__global__ void k_dinv(const int* __restrict__ cnt, float* __restrict__ dinv) {
    int i = blockIdx.x * blockDim.x + threadIdx.x;
    if (i < NN) dinv[i] = rsqrtf((float)(cnt[i] + 1));
}

// ---------------- GEMMs ----------------

// C[n x 64] = A[n x 64] @ B[64 x 64]; block=256, 64 rows per block
__global__ __launch_bounds__(256) void k_gemm64(const float* __restrict__ A,
                                                const float* __restrict__ B,
                                                float* __restrict__ C, int n) {
    __shared__ float Bs[64 * 64];
    int tid = threadIdx.x;
    for (int i = tid; i < 64 * 64; i += 256) Bs[i] = B[i];
    __syncthreads();
    int col = tid & 63;
    int rb = blockIdx.x * 64 + (tid >> 6) * 16;
    for (int r = 0; r < 16; ++r) {
        int row = rb + r;
        if (row >= n) return;
        const float* a = A + (size_t)row * 64;
        float acc = 0.f;
#pragma unroll
        for (int k = 0; k < 64; ++k) acc += a[k] * Bs[k * 64 + col];
        C[(size_t)row * 64 + col] = acc;
    }
}

// C[n x 256] = A[n x 64] @ B[64 x 256]; block=256, 16 rows per block
__global__ __launch_bounds__(256) void k_gemm256(const float* __restrict__ A,
                                                 const float* __restrict__ B,
                                                 float* __restrict__ C, int n) {
    __shared__ float Bs[64 * 256];  // 64 KB
    int tid = threadIdx.x;
    for (int i = tid; i < 64 * 256; i += 256) Bs[i] = B[i];
    __syncthreads();
    int col0 = tid & 63;
    int rb = blockIdx.x * 16 + (tid >> 6) * 4;
    for (int r = 0; r < 4; ++r) {
        int row = rb + r;
        if (row >= n) return;
        const float* a = A + (size_t)row * 64;
        float acc0 = 0.f, acc1 = 0.f, acc2 = 0.f, acc3 = 0.f;
#pragma unroll
        for (int k = 0; k < 64; ++k) {
            float av = a[k];
            acc0 += av * Bs[k * 256 + 0 * 64 + col0];
            acc1 += av * Bs[k * 256 + 1 * 64 + col0];
            acc2 += av * Bs[k * 256 + 2 * 64 + col0];
            acc3 += av * Bs[k * 256 + 3 * 64 + col0];
        }
        float* c = C + (size_t)row * 256;
        c[0 * 64 + col0] = acc0;
        c[1 * 64 + col0] = acc1;
        c[2 * 64 + col0] = acc2;
        c[3 * 64 + col0] = acc3;
    }
}

// ---------------- GCN aggregation: one wave/node, 4 edges in flight, float4 rows ----------------

__global__ __launch_bounds__(256) void k_gcn_agg(const float* __restrict__ hx,
                                                 const int* __restrict__ row_ptr,
                                                 const int* __restrict__ col,
                                                 const float* __restrict__ dinv,
                                                 const float* __restrict__ bias,
                                                 float* __restrict__ h) {
    int wid = (blockIdx.x * blockDim.x + threadIdx.x) >> 6;
    int lane = threadIdx.x & 63;
    if (wid >= NN) return;
    int sub = lane >> 4;    // which edge in the 4-group
    int fl  = lane & 15;    // float4 index within row (16 * 16B = 64 floats)
    int s0 = row_ptr[wid], s1 = row_ptr[wid + 1];
    float di = dinv[wid];
    const float4* hx4 = (const float4*)hx;
    float ax = 0.f, ay = 0.f, az = 0.f, aw = 0.f;
    for (int k = s0 + sub; k < s1; k += 4) {
        int s = col[k];
        float w = dinv[s] * di;
        float4 v = hx4[(size_t)s * 16 + fl];
        ax += w * v.x; ay += w * v.y; az += w * v.z; aw += w * v.w;
    }
    // combine the 4 edge-subgroups (lanes i, i+16, i+32, i+48)
    ax += __shfl_xor(ax, 16); ax += __shfl_xor(ax, 32);
    ay += __shfl_xor(ay, 16); ay += __shfl_xor(ay, 32);
    az += __shfl_xor(az, 16); az += __shfl_xor(az, 32);
    aw += __shfl_xor(aw, 16); aw += __shfl_xor(aw, 32);
    if (sub == 0) {
        float4 bb = ((const float4*)bias)[fl];
        float4 z;
        z.x = fmaxf(ax + bb.x, 0.f);
        z.y = fmaxf(ay + bb.y, 0.f);
        z.z = fmaxf(az + bb.z, 0.f);
        z.w = fmaxf(aw + bb.w, 0.f);
        ((float4*)(h + (size_t)wid * 64))[fl] = z;
    }
}

// ---------------- per-node attention logits a_s, a_d (float4 + 16-lane reduce) ----------------

__global__ __launch_bounds__(256) void k_att(const float* __restrict__ g,
                                             const float* __restrict__ att_src,
                                             const float* __restrict__ att_dst,
                                             float* __restrict__ a_s,
                                             float* __restrict__ a_d) {
    int wid = (blockIdx.x * blockDim.x + threadIdx.x) >> 6;
    int lane = threadIdx.x & 63;
    if (wid >= NN) return;
    float4 gv = ((const float4*)(g + (size_t)wid * 256))[lane];
    float4 as4 = ((const float4*)att_src)[lane];
    float4 ad4 = ((const float4*)att_dst)[lane];
    float vs = gv.x * as4.x + gv.y * as4.y + gv.z * as4.z + gv.w * as4.w;
    float vd = gv.x * ad4.x + gv.y * ad4.y + gv.z * ad4.z + gv.w * ad4.w;
#pragma unroll
    for (int off = 1; off < 16; off <<= 1) {
        vs += __shfl_xor(vs, off);
        vd += __shfl_xor(vd, off);
    }
    if ((lane & 15) == 0) {
        a_s[wid * 4 + (lane >> 4)] = vs;
        a_d[wid * 4 + (lane >> 4)] = vd;
    }
}

// ---------------- GAT: segment softmax + float4 row gathers + LDS block pooling ----------------

__device__ __forceinline__ float lrelu(float x) { return x > 0.f ? x : 0.2f * x; }

__global__ __launch_bounds__(256) void k_gat(const float* __restrict__ g,
                                             const float* __restrict__ a_s,
                                             const float* __restrict__ a_d,
                                             const int* __restrict__ row_ptr,
                                             const int* __restrict__ col,
                                             const float* __restrict__ gat_b,
                                             const int* __restrict__ batch,
                                             float* __restrict__ pool,
                                             float* __restrict__ cnt_g) {
    __shared__ float zpool[256];
    __shared__ int bids[4];
    int tid = threadIdx.x;
    int wv = tid >> 6, lane = tid & 63;
    int wid = blockIdx.x * 4 + wv;           // NN == 50000 == gridDim.x*4, always valid
    int hh = lane >> 4;                      // head owned by this lane in pass 3

    int s0 = row_ptr[wid], s1 = row_ptr[wid + 1];
    float ad0 = a_d[wid * 4 + 0], ad1 = a_d[wid * 4 + 1];
    float ad2 = a_d[wid * 4 + 2], ad3 = a_d[wid * 4 + 3];
    const float4* as4p = (const float4*)a_s;

    // pass 1: per-head max over incoming edges (lane-strided)
    float m0 = -1e30f, m1 = -1e30f, m2 = -1e30f, m3 = -1e30f;
    for (int k = s0 + lane; k < s1; k += 64) {
        int s = col[k];
        float4 av = as4p[s];
        m0 = fmaxf(m0, lrelu(av.x + ad0));
        m1 = fmaxf(m1, lrelu(av.y + ad1));
        m2 = fmaxf(m2, lrelu(av.z + ad2));
        m3 = fmaxf(m3, lrelu(av.w + ad3));
    }
#pragma unroll
    for (int off = 32; off; off >>= 1) {
        m0 = fmaxf(m0, __shfl_xor(m0, off));
        m1 = fmaxf(m1, __shfl_xor(m1, off));
        m2 = fmaxf(m2, __shfl_xor(m2, off));
        m3 = fmaxf(m3, __shfl_xor(m3, off));
    }

    // pass 2: per-head sum of exp
    float t0 = 0.f, t1 = 0.f, t2 = 0.f, t3 = 0.f;
    for (int k = s0 + lane; k < s1; k += 64) {
        int s = col[k];
        float4 av = as4p[s];
        t0 += __expf(lrelu(av.x + ad0) - m0);
        t1 += __expf(lrelu(av.y + ad1) - m1);
        t2 += __expf(lrelu(av.z + ad2) - m2);
        t3 += __expf(lrelu(av.w + ad3) - m3);
    }
#pragma unroll
    for (int off = 32; off; off >>= 1) {
        t0 += __shfl_xor(t0, off);
        t1 += __shfl_xor(t1, off);
        t2 += __shfl_xor(t2, off);
        t3 += __shfl_xor(t3, off);
    }

    // per-lane head selection
    float msel  = hh < 2 ? (hh == 0 ? m0 : m1) : (hh == 2 ? m2 : m3);
    float tsel  = hh < 2 ? (hh == 0 ? t0 : t1) : (hh == 2 ? t2 : t3);
    float adsel = hh < 2 ? (hh == 0 ? ad0 : ad1) : (hh == 2 ? ad2 : ad3);
    float rsel = 1.f / tsel;

    // pass 3: weighted aggregation; lane owns features [4*lane, 4*lane+3]
    float ax = 0.f, ay = 0.f, az = 0.f, aw = 0.f;
    const float4* g4 = (const float4*)g;
    for (int k = s0; k < s1; ++k) {
        int s = col[k];
        float w = __expf(lrelu(a_s[s * 4 + hh] + adsel) - msel) * rsel;
        float4 gv = g4[(size_t)s * 64 + lane];
        ax += w * gv.x; ay += w * gv.y; az += w * gv.z; aw += w * gv.w;
    }

    float4 gb = ((const float4*)gat_b)[lane];
    float zx = fmaxf(ax + gb.x, 0.f);
    float zy = fmaxf(ay + gb.y, 0.f);
    float zz = fmaxf(az + gb.z, 0.f);
    float zw = fmaxf(aw + gb.w, 0.f);

    int b = batch[wid];
    if (lane == 0) bids[wv] = b;
    zpool[tid] = 0.f;
    __syncthreads();
    bool uni = (bids[0] == bids[1]) && (bids[1] == bids[2]) && (bids[2] == bids[3]);
    if (uni) {
        // batch-sorted: ~96% of blocks are graph-uniform -> LDS reduce, 4x fewer atomics
        atomicAdd(&zpool[lane * 4 + 0], zx);
        atomicAdd(&zpool[lane * 4 + 1], zy);
        atomicAdd(&zpool[lane * 4 + 2], zz);
        atomicAdd(&zpool[lane * 4 + 3], zw);
        __syncthreads();
        if (wv == 0) {
            float* p = pool + (size_t)bids[0] * 256;
            atomicAdd(&p[lane * 4 + 0], zpool[lane * 4 + 0]);
            atomicAdd(&p[lane * 4 + 1], zpool[lane * 4 + 1]);
            atomicAdd(&p[lane * 4 + 2], zpool[lane * 4 + 2]);
            atomicAdd(&p[lane * 4 + 3], zpool[lane * 4 + 3]);
        }
        if (tid == 0) atomicAdd(&cnt_g[bids[0]], 4.0f);
    } else {
        __syncthreads();
        float* p = pool + (size_t)b * 256;
        atomicAdd(&p[lane * 4 + 0], zx);
        atomicAdd(&p[lane * 4 + 1], zy);
        atomicAdd(&p[lane * 4 + 2], zz);
        atomicAdd(&p[lane * 4 + 3], zw);
        if (lane == 0) atomicAdd(&cnt_g[b], 1.0f);
    }
}

// ---------------- output projection ----------------

__global__ void k_out(const float* __restrict__ pool, const float* __restrict__ cnt_g,
                      const float* __restrict__ W, const float* __restrict__ b,
                      float* __restrict__ out) {
    int idx = blockIdx.x * blockDim.x + threadIdx.x;
    if (idx >= NGRAPH * NOUT) return;
    int gg = idx >> 5, o = idx & 31;
    float c = cnt_g[gg];
    c = c > 1.f ? c : 1.f;
    float rinv = 1.f / c;
    const float* p = pool + (size_t)gg * 256;
    float acc = 0.f;
#pragma unroll 8
    for (int f = 0; f < 256; ++f) acc += p[f] * W[f * 32 + o];
    out[idx] = acc * rinv + b[o];
}

// ---------------- launch ----------------

extern "C" void kernel_launch(void* const* d_in, const int* in_sizes, int n_in,
                              void* d_out, int out_size, void* d_ws, size_t ws_size,
                              hipStream_t stream) {
    const float* x       = (const float*)d_in[0];
    const int*   eidx    = (const int*)d_in[1];
    const int*   batch   = (const int*)d_in[2];
    const float* gcn_W   = (const float*)d_in[3];
    const float* gcn_b   = (const float*)d_in[4];
    const float* gat_W   = (const float*)d_in[5];
    const float* att_src = (const float*)d_in[6];
    const float* att_dst = (const float*)d_in[7];
    const float* gat_b   = (const float*)d_in[8];
    const float* out_W   = (const float*)d_in[9];
    const float* out_b   = (const float*)d_in[10];
    float* out = (float*)d_out;

    const int* src = eidx;        // edge_index[0]
    const int* dst = eidx + NE;   // edge_index[1]

    size_t off = 0;
    auto carve = [&](size_t bytes) -> char* {
        char* p = (char*)d_ws + off;
        off += (bytes + 255) & ~(size_t)255;
        return p;
    };
    int*   cnt     = (int*)carve(NN * sizeof(int));
    int*   fill    = (int*)carve(NN * sizeof(int));
    int*   row_ptr = (int*)carve((NN + 1) * sizeof(int));
    int*   bsum    = (int*)carve(256 * sizeof(int));
    int*   colb    = (int*)carve((size_t)NEP * sizeof(int));
    float* dinv    = (float*)carve(NN * sizeof(float));
    float* hx      = (float*)carve((size_t)NN * 64 * sizeof(float));
    float* h       = (float*)carve((size_t)NN * 64 * sizeof(float));
    float* g       = (float*)carve((size_t)NN * 256 * sizeof(float));
    float* a_s     = (float*)carve((size_t)NN * 4 * sizeof(float));
    float* a_d     = (float*)carve((size_t)NN * 4 * sizeof(float));
    float* pool    = (float*)carve((size_t)NGRAPH * 256 * sizeof(float));
    float* cnt_g   = (float*)carve(NGRAPH * sizeof(float));

    hipMemsetAsync(cnt, 0, NN * sizeof(int), stream);
    hipMemsetAsync(fill, 0, NN * sizeof(int), stream);
    hipMemsetAsync(pool, 0, (size_t)NGRAPH * 256 * sizeof(float), stream);
    hipMemsetAsync(cnt_g, 0, NGRAPH * sizeof(float), stream);

    const int nblk = (NN + 255) / 256;  // 196

    // CSR build
    k_count<<<(NE + 255) / 256, 256, 0, stream>>>(dst, cnt);
    k_scan1<<<nblk, 256, 0, stream>>>(cnt, bsum);
    k_scan2<<<1, 256, 0, stream>>>(bsum, nblk);
    k_scan3<<<nblk, 256, 0, stream>>>(cnt, bsum, row_ptr);
    k_fill<<<(NEP + 255) / 256, 256, 0, stream>>>(src, dst, row_ptr, fill, colb);
    k_dinv<<<(NN + 255) / 256, 256, 0, stream>>>(cnt, dinv);

    // GCN
    k_gemm64<<<(NN + 63) / 64, 256, 0, stream>>>(x, gcn_W, hx, NN);
    k_gcn_agg<<<(NN * 64 + 255) / 256, 256, 0, stream>>>(hx, row_ptr, colb, dinv, gcn_b, h);

    // GAT
    k_gemm256<<<(NN + 15) / 16, 256, 0, stream>>>(h, gat_W, g, NN);
    k_att<<<(NN * 64 + 255) / 256, 256, 0, stream>>>(g, att_src, att_dst, a_s, a_d);
    k_gat<<<NN / 4, 256, 0, stream>>>(g, a_s, a_d, row_ptr, colb, gat_b, batch, pool, cnt_g);

    // output projection
    k_out<<<(NGRAPH * NOUT + 255) / 256, 256, 0, stream>>>(pool, cnt_g, out_W, out_b, out);
}

// Round 3
// 490.437 us; speedup vs baseline: 1.3877x; 1.0687x over previous
//
#include <hip/hip_runtime.h>
#include <math.h>

#define NN 50000
#define NE 800000
#define NEP (NE + NN)   // edges incl self-loops
#define NGRAPH 500
#define NOUT 32

// ---------------- CSR construction ----------------

__global__ void k_count(const int* __restrict__ dst, int* __restrict__ cnt) {
    int e = blockIdx.x * blockDim.x + threadIdx.x;
    if (e < NE) atomicAdd(&cnt[dst[e]], 1);
}

// pass 1: per-block sums of (cnt[i]+1)
__global__ __launch_bounds__(256) void k_scan1(const int* __restrict__ cnt, int* __restrict__ bsum) {
    __shared__ int buf[256];
    int i = blockIdx.x * 256 + threadIdx.x;
    int v = (i < NN) ? (cnt[i] + 1) : 0;
    buf[threadIdx.x] = v;
    __syncthreads();
    for (int off = 128; off; off >>= 1) {
        if (threadIdx.x < off) buf[threadIdx.x] += buf[threadIdx.x + off];
        __syncthreads();
    }
    if (threadIdx.x == 0) bsum[blockIdx.x] = buf[0];
}

// pass 2: exclusive scan of block sums (nblk <= 256), single block
__global__ __launch_bounds__(256) void k_scan2(int* __restrict__ bsum, int nblk) {
    __shared__ int buf[256];
    int tid = threadIdx.x;
    int v = (tid < nblk) ? bsum[tid] : 0;
    buf[tid] = v;
    __syncthreads();
    for (int off = 1; off < 256; off <<= 1) {
        int t = (tid >= off) ? buf[tid - off] : 0;
        __syncthreads();
        buf[tid] += t;
        __syncthreads();
    }
    if (tid < nblk) bsum[tid] = buf[tid] - v;  // exclusive
}

// pass 3: intra-block exclusive scan + block offset -> row_ptr; also dinv
__global__ __launch_bounds__(256) void k_scan3(const int* __restrict__ cnt,
                                               const int* __restrict__ bsum,
                                               int* __restrict__ row_ptr,
                                               float* __restrict__ dinv) {
    __shared__ int buf[256];
    int tid = threadIdx.x;
    int i = blockIdx.x * 256 + tid;
    int v = (i < NN) ? (cnt[i] + 1) : 0;
    buf[tid] = v;
    __syncthreads();
    for (int off = 1; off < 256; off <<= 1) {
        int t = (tid >= off) ? buf[tid - off] : 0;
        __syncthreads();
        buf[tid] += t;
        __syncthreads();
    }
    if (i < NN) {
        row_ptr[i] = bsum[blockIdx.x] + buf[tid] - v;
        dinv[i] = rsqrtf((float)(cnt[i] + 1));
    }
    if (i == NN - 1) row_ptr[NN] = bsum[blockIdx.x] + buf[tid];
}

__global__ void k_fill(const int* __restrict__ src, const int* __restrict__ dst,
                       const int* __restrict__ row_ptr, int* __restrict__ fill,
                       int* __restrict__ col) {
    int idx = blockIdx.x * blockDim.x + threadIdx.x;
    if (idx < NE) {
        int d = dst[idx];
        int p = row_ptr[d] + atomicAdd(&fill[d], 1);
        col[p] = src[idx];
    } else if (idx < NEP) {
        int i = idx - NE;
        int p = row_ptr[i] + atomicAdd(&fill[i], 1);
        col[p] = i;   // self loop
    }
}

// ---------------- GEMMs ----------------

// C[n x 64] = A[n x 64] @ B[64 x 64]; block=256, 64 rows per block
__global__ __launch_bounds__(256) void k_gemm64(const float* __restrict__ A,
                                                const float* __restrict__ B,
                                                float* __restrict__ C, int n) {
    __shared__ float Bs[64 * 64];
    int tid = threadIdx.x;
    for (int i = tid; i < 64 * 64; i += 256) Bs[i] = B[i];
    __syncthreads();
    int col = tid & 63;
    int rb = blockIdx.x * 64 + (tid >> 6) * 16;
    for (int r = 0; r < 16; ++r) {
        int row = rb + r;
        if (row >= n) return;
        const float* a = A + (size_t)row * 64;
        float acc = 0.f;
#pragma unroll
        for (int k = 0; k < 64; ++k) acc += a[k] * Bs[k * 64 + col];
        C[(size_t)row * 64 + col] = acc;
    }
}

// g[n x 256] = h[n x 64] @ W[64 x 256]  + fused attention logits a_s, a_d.
// Each 64-lane wave holds a full g-row (lane = col, acc0..3 = heads), so the
// per-head dot products with att_src/att_dst are 8 wave butterflies.
// NN % 16 == 0 -> every row valid, no guards (shuffles need full wave).
__global__ __launch_bounds__(256) void k_gemm256(const float* __restrict__ A,
                                                 const float* __restrict__ B,
                                                 const float* __restrict__ att_src,
                                                 const float* __restrict__ att_dst,
                                                 float* __restrict__ C,
                                                 float* __restrict__ a_s,
                                                 float* __restrict__ a_d) {
    __shared__ float Bs[64 * 256];  // 64 KB
    int tid = threadIdx.x;
    for (int i = tid; i < 64 * 256; i += 256) Bs[i] = B[i];
    __syncthreads();
    int col0 = tid & 63;
    int lane = col0;
    float as0 = att_src[0 * 64 + col0], as1 = att_src[1 * 64 + col0];
    float as2 = att_src[2 * 64 + col0], as3 = att_src[3 * 64 + col0];
    float ad0 = att_dst[0 * 64 + col0], ad1 = att_dst[1 * 64 + col0];
    float ad2 = att_dst[2 * 64 + col0], ad3 = att_dst[3 * 64 + col0];
    int rb = blockIdx.x * 16 + (tid >> 6) * 4;
#pragma unroll
    for (int r = 0; r < 4; ++r) {
        int row = rb + r;
        const float* a = A + (size_t)row * 64;
        float acc0 = 0.f, acc1 = 0.f, acc2 = 0.f, acc3 = 0.f;
#pragma unroll
        for (int k = 0; k < 64; ++k) {
            float av = a[k];
            acc0 += av * Bs[k * 256 + 0 * 64 + col0];
            acc1 += av * Bs[k * 256 + 1 * 64 + col0];
            acc2 += av * Bs[k * 256 + 2 * 64 + col0];
            acc3 += av * Bs[k * 256 + 3 * 64 + col0];
        }
        float* c = C + (size_t)row * 256;
        c[0 * 64 + col0] = acc0;
        c[1 * 64 + col0] = acc1;
        c[2 * 64 + col0] = acc2;
        c[3 * 64 + col0] = acc3;
        // fused attention logits
        float vs0 = acc0 * as0, vs1 = acc1 * as1, vs2 = acc2 * as2, vs3 = acc3 * as3;
        float vd0 = acc0 * ad0, vd1 = acc1 * ad1, vd2 = acc2 * ad2, vd3 = acc3 * ad3;
#pragma unroll
        for (int off = 32; off; off >>= 1) {
            vs0 += __shfl_xor(vs0, off); vs1 += __shfl_xor(vs1, off);
            vs2 += __shfl_xor(vs2, off); vs3 += __shfl_xor(vs3, off);
            vd0 += __shfl_xor(vd0, off); vd1 += __shfl_xor(vd1, off);
            vd2 += __shfl_xor(vd2, off); vd3 += __shfl_xor(vd3, off);
        }
        if (lane == 0) {
            a_s[row * 4 + 0] = vs0; a_s[row * 4 + 1] = vs1;
            a_s[row * 4 + 2] = vs2; a_s[row * 4 + 3] = vs3;
            a_d[row * 4 + 0] = vd0; a_d[row * 4 + 1] = vd1;
            a_d[row * 4 + 2] = vd2; a_d[row * 4 + 3] = vd3;
        }
    }
}

// ---------------- GCN aggregation: one wave/node, 4 edges in flight, float4 rows ----------------

__global__ __launch_bounds__(256) void k_gcn_agg(const float* __restrict__ hx,
                                                 const int* __restrict__ row_ptr,
                                                 const int* __restrict__ col,
                                                 const float* __restrict__ dinv,
                                                 const float* __restrict__ bias,
                                                 float* __restrict__ h) {
    int wid = (blockIdx.x * blockDim.x + threadIdx.x) >> 6;
    int lane = threadIdx.x & 63;
    if (wid >= NN) return;
    int sub = lane >> 4;    // which edge in the 4-group
    int fl  = lane & 15;    // float4 index within row (16 * 16B = 64 floats)
    int s0 = row_ptr[wid], s1 = row_ptr[wid + 1];
    float di = dinv[wid];
    const float4* hx4 = (const float4*)hx;
    float ax = 0.f, ay = 0.f, az = 0.f, aw = 0.f;
    for (int k = s0 + sub; k < s1; k += 4) {
        int s = col[k];
        float w = dinv[s] * di;
        float4 v = hx4[(size_t)s * 16 + fl];
        ax += w * v.x; ay += w * v.y; az += w * v.z; aw += w * v.w;
    }
    ax += __shfl_xor(ax, 16); ax += __shfl_xor(ax, 32);
    ay += __shfl_xor(ay, 16); ay += __shfl_xor(ay, 32);
    az += __shfl_xor(az, 16); az += __shfl_xor(az, 32);
    aw += __shfl_xor(aw, 16); aw += __shfl_xor(aw, 32);
    if (sub == 0) {
        float4 bb = ((const float4*)bias)[fl];
        float4 z;
        z.x = fmaxf(ax + bb.x, 0.f);
        z.y = fmaxf(ay + bb.y, 0.f);
        z.z = fmaxf(az + bb.z, 0.f);
        z.w = fmaxf(aw + bb.w, 0.f);
        ((float4*)(h + (size_t)wid * 64))[fl] = z;
    }
}

// ---------------- GAT: single-pass online softmax, 4 g-rows in flight ----------------

__device__ __forceinline__ float lrelu(float x) { return x > 0.f ? x : 0.2f * x; }

__global__ __launch_bounds__(256) void k_gat(const float* __restrict__ g,
                                             const float* __restrict__ a_s,
                                             const float* __restrict__ a_d,
                                             const int* __restrict__ row_ptr,
                                             const int* __restrict__ col,
                                             const float* __restrict__ gat_b,
                                             const int* __restrict__ batch,
                                             float* __restrict__ pool,
                                             float* __restrict__ cnt_g) {
    __shared__ float zpool[256];
    __shared__ int bids[4];
    int tid = threadIdx.x;
    int wv = tid >> 6, lane = tid & 63;
    int wid = blockIdx.x * 4 + wv;           // NN == gridDim.x*4, always valid
    int hh = lane >> 4;                      // head owned by this lane

    int s0 = row_ptr[wid], s1 = row_ptr[wid + 1];
    float adsel = a_d[wid * 4 + hh];
    const float4* g4 = (const float4*)g;

    // online softmax state (uniform within each 16-lane head group)
    float m = -1e30f, t = 0.f;
    float ax = 0.f, ay = 0.f, az = 0.f, aw = 0.f;

    int k = s0;
    for (; k + 3 < s1; k += 4) {
        int i0 = col[k], i1 = col[k + 1], i2 = col[k + 2], i3 = col[k + 3];
        float e0 = lrelu(a_s[i0 * 4 + hh] + adsel);
        float e1 = lrelu(a_s[i1 * 4 + hh] + adsel);
        float e2 = lrelu(a_s[i2 * 4 + hh] + adsel);
        float e3 = lrelu(a_s[i3 * 4 + hh] + adsel);
        float4 g0 = g4[(size_t)i0 * 64 + lane];
        float4 g1 = g4[(size_t)i1 * 64 + lane];
        float4 g2 = g4[(size_t)i2 * 64 + lane];
        float4 g3 = g4[(size_t)i3 * 64 + lane];
        float mn = fmaxf(fmaxf(fmaxf(e0, e1), fmaxf(e2, e3)), m);
        float c = __expf(m - mn);
        float w0 = __expf(e0 - mn), w1 = __expf(e1 - mn);
        float w2 = __expf(e2 - mn), w3 = __expf(e3 - mn);
        t = t * c + (w0 + w1) + (w2 + w3);
        ax = ax * c + w0 * g0.x + w1 * g1.x + w2 * g2.x + w3 * g3.x;
        ay = ay * c + w0 * g0.y + w1 * g1.y + w2 * g2.y + w3 * g3.y;
        az = az * c + w0 * g0.z + w1 * g1.z + w2 * g2.z + w3 * g3.z;
        aw = aw * c + w0 * g0.w + w1 * g1.w + w2 * g2.w + w3 * g3.w;
        m = mn;
    }
    for (; k < s1; ++k) {
        int s = col[k];
        float e = lrelu(a_s[s * 4 + hh] + adsel);
        float4 gv = g4[(size_t)s * 64 + lane];
        float mn = fmaxf(m, e);
        float c = __expf(m - mn);
        float w = __expf(e - mn);
        t = t * c + w;
        ax = ax * c + w * gv.x;
        ay = ay * c + w * gv.y;
        az = az * c + w * gv.z;
        aw = aw * c + w * gv.w;
        m = mn;
    }
    float r = 1.f / t;

    float4 gb = ((const float4*)gat_b)[lane];
    float zx = fmaxf(ax * r + gb.x, 0.f);
    float zy = fmaxf(ay * r + gb.y, 0.f);
    float zz = fmaxf(az * r + gb.z, 0.f);
    float zw = fmaxf(aw * r + gb.w, 0.f);

    int b = batch[wid];
    if (lane == 0) bids[wv] = b;
    zpool[tid] = 0.f;
    __syncthreads();
    bool uni = (bids[0] == bids[1]) && (bids[1] == bids[2]) && (bids[2] == bids[3]);
    if (uni) {
        atomicAdd(&zpool[lane * 4 + 0], zx);
        atomicAdd(&zpool[lane * 4 + 1], zy);
        atomicAdd(&zpool[lane * 4 + 2], zz);
        atomicAdd(&zpool[lane * 4 + 3], zw);
        __syncthreads();
        if (wv == 0) {
            float* p = pool + (size_t)bids[0] * 256;
            atomicAdd(&p[lane * 4 + 0], zpool[lane * 4 + 0]);
            atomicAdd(&p[lane * 4 + 1], zpool[lane * 4 + 1]);
            atomicAdd(&p[lane * 4 + 2], zpool[lane * 4 + 2]);
            atomicAdd(&p[lane * 4 + 3], zpool[lane * 4 + 3]);
        }
        if (tid == 0) atomicAdd(&cnt_g[bids[0]], 4.0f);
    } else {
        __syncthreads();
        float* p = pool + (size_t)b * 256;
        atomicAdd(&p[lane * 4 + 0], zx);
        atomicAdd(&p[lane * 4 + 1], zy);
        atomicAdd(&p[lane * 4 + 2], zz);
        atomicAdd(&p[lane * 4 + 3], zw);
        if (lane == 0) atomicAdd(&cnt_g[b], 1.0f);
    }
}

// ---------------- output projection ----------------

__global__ void k_out(const float* __restrict__ pool, const float* __restrict__ cnt_g,
                      const float* __restrict__ W, const float* __restrict__ b,
                      float* __restrict__ out) {
    int idx = blockIdx.x * blockDim.x + threadIdx.x;
    if (idx >= NGRAPH * NOUT) return;
    int gg = idx >> 5, o = idx & 31;
    float c = cnt_g[gg];
    c = c > 1.f ? c : 1.f;
    float rinv = 1.f / c;
    const float* p = pool + (size_t)gg * 256;
    float acc = 0.f;
#pragma unroll 8
    for (int f = 0; f < 256; ++f) acc += p[f] * W[f * 32 + o];
    out[idx] = acc * rinv + b[o];
}

// ---------------- launch ----------------

extern "C" void kernel_launch(void* const* d_in, const int* in_sizes, int n_in,
                              void* d_out, int out_size, void* d_ws, size_t ws_size,
                              hipStream_t stream) {
    const float* x       = (const float*)d_in[0];
    const int*   eidx    = (const int*)d_in[1];
    const int*   batch   = (const int*)d_in[2];
    const float* gcn_W   = (const float*)d_in[3];
    const float* gcn_b   = (const float*)d_in[4];
    const float* gat_W   = (const float*)d_in[5];
    const float* att_src = (const float*)d_in[6];
    const float* att_dst = (const float*)d_in[7];
    const float* gat_b   = (const float*)d_in[8];
    const float* out_W   = (const float*)d_in[9];
    const float* out_b   = (const float*)d_in[10];
    float* out = (float*)d_out;

    const int* src = eidx;        // edge_index[0]
    const int* dst = eidx + NE;   // edge_index[1]

    size_t off = 0;
    auto carve = [&](size_t bytes) -> char* {
        char* p = (char*)d_ws + off;
        off += (bytes + 255) & ~(size_t)255;
        return p;
    };
    int*   cnt     = (int*)carve(NN * sizeof(int));
    int*   fill    = (int*)carve(NN * sizeof(int));
    int*   row_ptr = (int*)carve((NN + 1) * sizeof(int));
    int*   bsum    = (int*)carve(256 * sizeof(int));
    int*   colb    = (int*)carve((size_t)NEP * sizeof(int));
    float* dinv    = (float*)carve(NN * sizeof(float));
    float* hx      = (float*)carve((size_t)NN * 64 * sizeof(float));
    float* h       = (float*)carve((size_t)NN * 64 * sizeof(float));
    float* g       = (float*)carve((size_t)NN * 256 * sizeof(float));
    float* a_s     = (float*)carve((size_t)NN * 4 * sizeof(float));
    float* a_d     = (float*)carve((size_t)NN * 4 * sizeof(float));
    float* pool    = (float*)carve((size_t)NGRAPH * 256 * sizeof(float));
    float* cnt_g   = (float*)carve(NGRAPH * sizeof(float));

    hipMemsetAsync(cnt, 0, NN * sizeof(int), stream);
    hipMemsetAsync(fill, 0, NN * sizeof(int), stream);
    hipMemsetAsync(pool, 0, (size_t)NGRAPH * 256 * sizeof(float), stream);
    hipMemsetAsync(cnt_g, 0, NGRAPH * sizeof(float), stream);

    const int nblk = (NN + 255) / 256;  // 196

    // CSR build
    k_count<<<(NE + 255) / 256, 256, 0, stream>>>(dst, cnt);
    k_scan1<<<nblk, 256, 0, stream>>>(cnt, bsum);
    k_scan2<<<1, 256, 0, stream>>>(bsum, nblk);
    k_scan3<<<nblk, 256, 0, stream>>>(cnt, bsum, row_ptr, dinv);
    k_fill<<<(NEP + 255) / 256, 256, 0, stream>>>(src, dst, row_ptr, fill, colb);

    // GCN
    k_gemm64<<<(NN + 63) / 64, 256, 0, stream>>>(x, gcn_W, hx, NN);
    k_gcn_agg<<<(NN * 64 + 255) / 256, 256, 0, stream>>>(hx, row_ptr, colb, dinv, gcn_b, h);

    // GAT (gemm + fused attention logits, then single-pass online softmax agg)
    k_gemm256<<<NN / 16, 256, 0, stream>>>(h, gat_W, att_src, att_dst, g, a_s, a_d);
    k_gat<<<NN / 4, 256, 0, stream>>>(g, a_s, a_d, row_ptr, colb, gat_b, batch, pool, cnt_g);

    // output projection
    k_out<<<(NGRAPH * NOUT + 255) / 256, 256, 0, stream>>>(pool, cnt_g, out_W, out_b, out);
}

// Round 4
// 429.862 us; speedup vs baseline: 1.5832x; 1.1409x over previous
//
#include <hip/hip_runtime.h>
#include <math.h>

#define NN 50000
#define NE 800000
#define NEP (NE + NN)   // edges incl self-loops
#define NGRAPH 500
#define NOUT 32

// ---------------- CSR construction ----------------

__global__ void k_count(const int* __restrict__ dst, int* __restrict__ cnt) {
    int e = blockIdx.x * blockDim.x + threadIdx.x;
    if (e < NE) atomicAdd(&cnt[dst[e]], 1);
}

// pass 1: per-block sums of (cnt[i]+1)
__global__ __launch_bounds__(256) void k_scan1(const int* __restrict__ cnt, int* __restrict__ bsum) {
    __shared__ int buf[256];
    int i = blockIdx.x * 256 + threadIdx.x;
    int v = (i < NN) ? (cnt[i] + 1) : 0;
    buf[threadIdx.x] = v;
    __syncthreads();
    for (int off = 128; off; off >>= 1) {
        if (threadIdx.x < off) buf[threadIdx.x] += buf[threadIdx.x + off];
        __syncthreads();
    }
    if (threadIdx.x == 0) bsum[blockIdx.x] = buf[0];
}

// pass 2: exclusive scan of block sums (nblk <= 256), single block
__global__ __launch_bounds__(256) void k_scan2(int* __restrict__ bsum, int nblk) {
    __shared__ int buf[256];
    int tid = threadIdx.x;
    int v = (tid < nblk) ? bsum[tid] : 0;
    buf[tid] = v;
    __syncthreads();
    for (int off = 1; off < 256; off <<= 1) {
        int t = (tid >= off) ? buf[tid - off] : 0;
        __syncthreads();
        buf[tid] += t;
        __syncthreads();
    }
    if (tid < nblk) bsum[tid] = buf[tid] - v;  // exclusive
}

// pass 3: intra-block exclusive scan + block offset -> row_ptr; also dinv
__global__ __launch_bounds__(256) void k_scan3(const int* __restrict__ cnt,
                                               const int* __restrict__ bsum,
                                               int* __restrict__ row_ptr,
                                               float* __restrict__ dinv) {
    __shared__ int buf[256];
    int tid = threadIdx.x;
    int i = blockIdx.x * 256 + tid;
    int v = (i < NN) ? (cnt[i] + 1) : 0;
    buf[tid] = v;
    __syncthreads();
    for (int off = 1; off < 256; off <<= 1) {
        int t = (tid >= off) ? buf[tid - off] : 0;
        __syncthreads();
        buf[tid] += t;
        __syncthreads();
    }
    if (i < NN) {
        row_ptr[i] = bsum[blockIdx.x] + buf[tid] - v;
        dinv[i] = rsqrtf((float)(cnt[i] + 1));
    }
    if (i == NN - 1) row_ptr[NN] = bsum[blockIdx.x] + buf[tid];
}

__global__ void k_fill(const int* __restrict__ src, const int* __restrict__ dst,
                       const int* __restrict__ row_ptr, int* __restrict__ fill,
                       int* __restrict__ col) {
    int idx = blockIdx.x * blockDim.x + threadIdx.x;
    if (idx < NE) {
        int d = dst[idx];
        int p = row_ptr[d] + atomicAdd(&fill[d], 1);
        col[p] = src[idx];
    } else if (idx < NEP) {
        int i = idx - NE;
        int p = row_ptr[i] + atomicAdd(&fill[i], 1);
        col[p] = i;   // self loop
    }
}

// ---------------- GEMMs ----------------

// C[n x 64] = A[n x 64] @ B[64 x 64]; block=256, 64 rows/block.
// lane = 16-lane sub (4 rows each) x float4-col; one ds_read_b128 of B
// serves 4 rows (16 FMA). As padded to stride 68 floats (17 float4) to
// avoid a 4-way bank conflict on the sub-strided broadcast reads.
__global__ __launch_bounds__(256) void k_gemm64(const float* __restrict__ A,
                                                const float* __restrict__ B,
                                                float* __restrict__ C, int n) {
    __shared__ float Bs[64 * 64];    // 16 KB
    __shared__ float As[64 * 68];    // 17 KB, stride 68
    int tid = threadIdx.x;
    int rb = blockIdx.x * 64;
    for (int i = tid; i < 1024; i += 256) ((float4*)Bs)[i] = ((const float4*)B)[i];
    for (int i = tid; i < 1024; i += 256) {
        int r = i >> 4, c = i & 15;
        int row = rb + r; if (row >= n) row = n - 1;
        ((float4*)As)[r * 17 + c] = ((const float4*)A)[(size_t)row * 16 + c];
    }
    __syncthreads();
    int lane = tid & 63, wv = tid >> 6;
    int fl = lane & 15, sub = lane >> 4;
    int r0 = wv * 16 + sub * 4;      // first of 4 rows (within tile)
    const float4* Bs4 = (const float4*)Bs;
    float4 acc0 = {0,0,0,0}, acc1 = {0,0,0,0}, acc2 = {0,0,0,0}, acc3 = {0,0,0,0};
#pragma unroll 4
    for (int k = 0; k < 64; ++k) {
        float4 b4 = Bs4[k * 16 + fl];
        float a0 = As[(r0 + 0) * 68 + k];
        float a1 = As[(r0 + 1) * 68 + k];
        float a2 = As[(r0 + 2) * 68 + k];
        float a3 = As[(r0 + 3) * 68 + k];
        acc0.x += a0 * b4.x; acc0.y += a0 * b4.y; acc0.z += a0 * b4.z; acc0.w += a0 * b4.w;
        acc1.x += a1 * b4.x; acc1.y += a1 * b4.y; acc1.z += a1 * b4.z; acc1.w += a1 * b4.w;
        acc2.x += a2 * b4.x; acc2.y += a2 * b4.y; acc2.z += a2 * b4.z; acc2.w += a2 * b4.w;
        acc3.x += a3 * b4.x; acc3.y += a3 * b4.y; acc3.z += a3 * b4.z; acc3.w += a3 * b4.w;
    }
    int row = rb + r0;
    if (row + 0 < n) ((float4*)(C + (size_t)(row + 0) * 64))[fl] = acc0;
    if (row + 1 < n) ((float4*)(C + (size_t)(row + 1) * 64))[fl] = acc1;
    if (row + 2 < n) ((float4*)(C + (size_t)(row + 2) * 64))[fl] = acc2;
    if (row + 3 < n) ((float4*)(C + (size_t)(row + 3) * 64))[fl] = acc3;
}

// g[n x 256] = h[n x 64] @ W[64 x 256] + fused attention logits.
// Block = 4 waves x 8 rows = 32 rows. Lane owns cols [4*lane, 4*lane+3]
// (all within head lane>>4). One ds_read_b128 of W serves 8 rows (32 FMA).
__global__ __launch_bounds__(256) void k_gemm256(const float* __restrict__ A,
                                                 const float* __restrict__ B,
                                                 const float* __restrict__ att_src,
                                                 const float* __restrict__ att_dst,
                                                 float* __restrict__ C,
                                                 float* __restrict__ a_s,
                                                 float* __restrict__ a_d) {
    __shared__ float Bs[64 * 256];   // 64 KB
    __shared__ float As[32 * 64];    // 8 KB
    int tid = threadIdx.x;
    int rb = blockIdx.x * 32;
    for (int i = tid; i < 4096; i += 256) ((float4*)Bs)[i] = ((const float4*)B)[i];
    for (int i = tid; i < 512; i += 256) {
        int r = i >> 4, c = i & 15;
        int row = rb + r; if (row >= NN) row = NN - 1;
        ((float4*)As)[i] = ((const float4*)A)[(size_t)row * 16 + c];
    }
    __syncthreads();
    int lane = tid & 63, wv = tid >> 6;
    const float4* Bs4 = (const float4*)Bs;
    float4 as4 = ((const float4*)att_src)[lane];
    float4 ad4 = ((const float4*)att_dst)[lane];
    const float* Aw = As + (wv * 8) * 64;
    float4 acc[8];
#pragma unroll
    for (int r = 0; r < 8; ++r) acc[r] = make_float4(0.f, 0.f, 0.f, 0.f);
#pragma unroll 4
    for (int k = 0; k < 64; ++k) {
        float4 b4 = Bs4[k * 64 + lane];
#pragma unroll
        for (int r = 0; r < 8; ++r) {
            float av = Aw[r * 64 + k];
            acc[r].x += av * b4.x; acc[r].y += av * b4.y;
            acc[r].z += av * b4.z; acc[r].w += av * b4.w;
        }
    }
#pragma unroll
    for (int r = 0; r < 8; ++r) {
        int row = rb + wv * 8 + r;
        bool valid = row < NN;   // wave-uniform
        if (valid) ((float4*)(C + (size_t)row * 256))[lane] = acc[r];
        float vs = acc[r].x * as4.x + acc[r].y * as4.y + acc[r].z * as4.z + acc[r].w * as4.w;
        float vd = acc[r].x * ad4.x + acc[r].y * ad4.y + acc[r].z * ad4.z + acc[r].w * ad4.w;
#pragma unroll
        for (int off = 1; off < 16; off <<= 1) {
            vs += __shfl_xor(vs, off);
            vd += __shfl_xor(vd, off);
        }
        if (valid && (lane & 15) == 0) {
            a_s[row * 4 + (lane >> 4)] = vs;
            a_d[row * 4 + (lane >> 4)] = vd;
        }
    }
}

// ---------------- GCN aggregation: one wave/node, 8 edges in flight ----------------

__global__ __launch_bounds__(256) void k_gcn_agg(const float* __restrict__ hx,
                                                 const int* __restrict__ row_ptr,
                                                 const int* __restrict__ col,
                                                 const float* __restrict__ dinv,
                                                 const float* __restrict__ bias,
                                                 float* __restrict__ h) {
    int wid = (blockIdx.x * blockDim.x + threadIdx.x) >> 6;
    int lane = threadIdx.x & 63;
    if (wid >= NN) return;
    int sub = lane >> 4;    // edge slot within 4-group
    int fl  = lane & 15;    // float4 index within row
    int s0 = row_ptr[wid], s1 = row_ptr[wid + 1];
    float di = dinv[wid];
    const float4* hx4 = (const float4*)hx;
    float ax = 0.f, ay = 0.f, az = 0.f, aw = 0.f;
    int k = s0 + sub;
    for (; k + 4 < s1; k += 8) {
        int sA = col[k], sB = col[k + 4];
        float wA = dinv[sA] * di, wB = dinv[sB] * di;
        float4 vA = hx4[(size_t)sA * 16 + fl];
        float4 vB = hx4[(size_t)sB * 16 + fl];
        ax += wA * vA.x + wB * vB.x;
        ay += wA * vA.y + wB * vB.y;
        az += wA * vA.z + wB * vB.z;
        aw += wA * vA.w + wB * vB.w;
    }
    if (k < s1) {
        int s = col[k];
        float w = dinv[s] * di;
        float4 v = hx4[(size_t)s * 16 + fl];
        ax += w * v.x; ay += w * v.y; az += w * v.z; aw += w * v.w;
    }
    ax += __shfl_xor(ax, 16); ax += __shfl_xor(ax, 32);
    ay += __shfl_xor(ay, 16); ay += __shfl_xor(ay, 32);
    az += __shfl_xor(az, 16); az += __shfl_xor(az, 32);
    aw += __shfl_xor(aw, 16); aw += __shfl_xor(aw, 32);
    if (sub == 0) {
        float4 bb = ((const float4*)bias)[fl];
        float4 z;
        z.x = fmaxf(ax + bb.x, 0.f);
        z.y = fmaxf(ay + bb.y, 0.f);
        z.z = fmaxf(az + bb.z, 0.f);
        z.w = fmaxf(aw + bb.w, 0.f);
        ((float4*)(h + (size_t)wid * 64))[fl] = z;
    }
}

// ---------------- GAT: single-pass online softmax, 8 g-rows in flight ----------------

__device__ __forceinline__ float lrelu(float x) { return x > 0.f ? x : 0.2f * x; }

__global__ __launch_bounds__(256) void k_gat(const float* __restrict__ g,
                                             const float* __restrict__ a_s,
                                             const float* __restrict__ a_d,
                                             const int* __restrict__ row_ptr,
                                             const int* __restrict__ col,
                                             const float* __restrict__ gat_b,
                                             const int* __restrict__ batch,
                                             float* __restrict__ pool,
                                             float* __restrict__ cnt_g) {
    __shared__ float zpool[256];
    __shared__ int bids[4];
    int tid = threadIdx.x;
    int wv = tid >> 6, lane = tid & 63;
    int wid = blockIdx.x * 4 + wv;           // NN == gridDim.x*4, always valid
    int hh = lane >> 4;                      // head owned by this lane

    int s0 = row_ptr[wid], s1 = row_ptr[wid + 1];
    float adsel = a_d[wid * 4 + hh];
    const float4* g4 = (const float4*)g;

    float m = -1e30f, t = 0.f;
    float ax = 0.f, ay = 0.f, az = 0.f, aw = 0.f;

    int k = s0;
    for (; k + 7 < s1; k += 8) {
        int i0 = col[k], i1 = col[k + 1], i2 = col[k + 2], i3 = col[k + 3];
        int i4 = col[k + 4], i5 = col[k + 5], i6 = col[k + 6], i7 = col[k + 7];
        float e0 = lrelu(a_s[i0 * 4 + hh] + adsel);
        float e1 = lrelu(a_s[i1 * 4 + hh] + adsel);
        float e2 = lrelu(a_s[i2 * 4 + hh] + adsel);
        float e3 = lrelu(a_s[i3 * 4 + hh] + adsel);
        float e4 = lrelu(a_s[i4 * 4 + hh] + adsel);
        float e5 = lrelu(a_s[i5 * 4 + hh] + adsel);
        float e6 = lrelu(a_s[i6 * 4 + hh] + adsel);
        float e7 = lrelu(a_s[i7 * 4 + hh] + adsel);
        float4 g0 = g4[(size_t)i0 * 64 + lane];
        float4 g1 = g4[(size_t)i1 * 64 + lane];
        float4 g2 = g4[(size_t)i2 * 64 + lane];
        float4 g3 = g4[(size_t)i3 * 64 + lane];
        float4 g5v = g4[(size_t)i5 * 64 + lane];
        float4 g4v = g4[(size_t)i4 * 64 + lane];
        float4 g6 = g4[(size_t)i6 * 64 + lane];
        float4 g7 = g4[(size_t)i7 * 64 + lane];
        float mn = fmaxf(fmaxf(fmaxf(e0, e1), fmaxf(e2, e3)),
                         fmaxf(fmaxf(e4, e5), fmaxf(e6, e7)));
        mn = fmaxf(mn, m);
        float c = __expf(m - mn);
        float w0 = __expf(e0 - mn), w1 = __expf(e1 - mn);
        float w2 = __expf(e2 - mn), w3 = __expf(e3 - mn);
        float w4 = __expf(e4 - mn), w5 = __expf(e5 - mn);
        float w6 = __expf(e6 - mn), w7 = __expf(e7 - mn);
        t = t * c + ((w0 + w1) + (w2 + w3)) + ((w4 + w5) + (w6 + w7));
        ax = ax * c + w0 * g0.x + w1 * g1.x + w2 * g2.x + w3 * g3.x
                    + w4 * g4v.x + w5 * g5v.x + w6 * g6.x + w7 * g7.x;
        ay = ay * c + w0 * g0.y + w1 * g1.y + w2 * g2.y + w3 * g3.y
                    + w4 * g4v.y + w5 * g5v.y + w6 * g6.y + w7 * g7.y;
        az = az * c + w0 * g0.z + w1 * g1.z + w2 * g2.z + w3 * g3.z
                    + w4 * g4v.z + w5 * g5v.z + w6 * g6.z + w7 * g7.z;
        aw = aw * c + w0 * g0.w + w1 * g1.w + w2 * g2.w + w3 * g3.w
                    + w4 * g4v.w + w5 * g5v.w + w6 * g6.w + w7 * g7.w;
        m = mn;
    }
    for (; k + 3 < s1; k += 4) {
        int i0 = col[k], i1 = col[k + 1], i2 = col[k + 2], i3 = col[k + 3];
        float e0 = lrelu(a_s[i0 * 4 + hh] + adsel);
        float e1 = lrelu(a_s[i1 * 4 + hh] + adsel);
        float e2 = lrelu(a_s[i2 * 4 + hh] + adsel);
        float e3 = lrelu(a_s[i3 * 4 + hh] + adsel);
        float4 g0 = g4[(size_t)i0 * 64 + lane];
        float4 g1 = g4[(size_t)i1 * 64 + lane];
        float4 g2 = g4[(size_t)i2 * 64 + lane];
        float4 g3 = g4[(size_t)i3 * 64 + lane];
        float mn = fmaxf(fmaxf(fmaxf(e0, e1), fmaxf(e2, e3)), m);
        float c = __expf(m - mn);
        float w0 = __expf(e0 - mn), w1 = __expf(e1 - mn);
        float w2 = __expf(e2 - mn), w3 = __expf(e3 - mn);
        t = t * c + (w0 + w1) + (w2 + w3);
        ax = ax * c + w0 * g0.x + w1 * g1.x + w2 * g2.x + w3 * g3.x;
        ay = ay * c + w0 * g0.y + w1 * g1.y + w2 * g2.y + w3 * g3.y;
        az = az * c + w0 * g0.z + w1 * g1.z + w2 * g2.z + w3 * g3.z;
        aw = aw * c + w0 * g0.w + w1 * g1.w + w2 * g2.w + w3 * g3.w;
        m = mn;
    }
    for (; k < s1; ++k) {
        int s = col[k];
        float e = lrelu(a_s[s * 4 + hh] + adsel);
        float4 gv = g4[(size_t)s * 64 + lane];
        float mn = fmaxf(m, e);
        float c = __expf(m - mn);
        float w = __expf(e - mn);
        t = t * c + w;
        ax = ax * c + w * gv.x;
        ay = ay * c + w * gv.y;
        az = az * c + w * gv.z;
        aw = aw * c + w * gv.w;
        m = mn;
    }
    float r = 1.f / t;

    float4 gb = ((const float4*)gat_b)[lane];
    float zx = fmaxf(ax * r + gb.x, 0.f);
    float zy = fmaxf(ay * r + gb.y, 0.f);
    float zz = fmaxf(az * r + gb.z, 0.f);
    float zw = fmaxf(aw * r + gb.w, 0.f);

    int b = batch[wid];
    if (lane == 0) bids[wv] = b;
    zpool[tid] = 0.f;
    __syncthreads();
    bool uni = (bids[0] == bids[1]) && (bids[1] == bids[2]) && (bids[2] == bids[3]);
    if (uni) {
        atomicAdd(&zpool[lane * 4 + 0], zx);
        atomicAdd(&zpool[lane * 4 + 1], zy);
        atomicAdd(&zpool[lane * 4 + 2], zz);
        atomicAdd(&zpool[lane * 4 + 3], zw);
        __syncthreads();
        if (wv == 0) {
            float* p = pool + (size_t)bids[0] * 256;
            atomicAdd(&p[lane * 4 + 0], zpool[lane * 4 + 0]);
            atomicAdd(&p[lane * 4 + 1], zpool[lane * 4 + 1]);
            atomicAdd(&p[lane * 4 + 2], zpool[lane * 4 + 2]);
            atomicAdd(&p[lane * 4 + 3], zpool[lane * 4 + 3]);
        }
        if (tid == 0) atomicAdd(&cnt_g[bids[0]], 4.0f);
    } else {
        __syncthreads();
        float* p = pool + (size_t)b * 256;
        atomicAdd(&p[lane * 4 + 0], zx);
        atomicAdd(&p[lane * 4 + 1], zy);
        atomicAdd(&p[lane * 4 + 2], zz);
        atomicAdd(&p[lane * 4 + 3], zw);
        if (lane == 0) atomicAdd(&cnt_g[b], 1.0f);
    }
}

// ---------------- output projection ----------------

__global__ void k_out(const float* __restrict__ pool, const float* __restrict__ cnt_g,
                      const float* __restrict__ W, const float* __restrict__ b,
                      float* __restrict__ out) {
    int idx = blockIdx.x * blockDim.x + threadIdx.x;
    if (idx >= NGRAPH * NOUT) return;
    int gg = idx >> 5, o = idx & 31;
    float c = cnt_g[gg];
    c = c > 1.f ? c : 1.f;
    float rinv = 1.f / c;
    const float* p = pool + (size_t)gg * 256;
    float acc = 0.f;
#pragma unroll 8
    for (int f = 0; f < 256; ++f) acc += p[f] * W[f * 32 + o];
    out[idx] = acc * rinv + b[o];
}

// ---------------- launch ----------------

extern "C" void kernel_launch(void* const* d_in, const int* in_sizes, int n_in,
                              void* d_out, int out_size, void* d_ws, size_t ws_size,
                              hipStream_t stream) {
    const float* x       = (const float*)d_in[0];
    const int*   eidx    = (const int*)d_in[1];
    const int*   batch   = (const int*)d_in[2];
    const float* gcn_W   = (const float*)d_in[3];
    const float* gcn_b   = (const float*)d_in[4];
    const float* gat_W   = (const float*)d_in[5];
    const float* att_src = (const float*)d_in[6];
    const float* att_dst = (const float*)d_in[7];
    const float* gat_b   = (const float*)d_in[8];
    const float* out_W   = (const float*)d_in[9];
    const float* out_b   = (const float*)d_in[10];
    float* out = (float*)d_out;

    const int* src = eidx;        // edge_index[0]
    const int* dst = eidx + NE;   // edge_index[1]

    size_t off = 0;
    auto carve = [&](size_t bytes) -> char* {
        char* p = (char*)d_ws + off;
        off += (bytes + 255) & ~(size_t)255;
        return p;
    };
    int*   cnt     = (int*)carve(NN * sizeof(int));
    int*   fill    = (int*)carve(NN * sizeof(int));
    int*   row_ptr = (int*)carve((NN + 1) * sizeof(int));
    int*   bsum    = (int*)carve(256 * sizeof(int));
    int*   colb    = (int*)carve((size_t)NEP * sizeof(int));
    float* dinv    = (float*)carve(NN * sizeof(float));
    float* hx      = (float*)carve((size_t)NN * 64 * sizeof(float));
    float* h       = (float*)carve((size_t)NN * 64 * sizeof(float));
    float* g       = (float*)carve((size_t)NN * 256 * sizeof(float));
    float* a_s     = (float*)carve((size_t)NN * 4 * sizeof(float));
    float* a_d     = (float*)carve((size_t)NN * 4 * sizeof(float));
    float* pool    = (float*)carve((size_t)NGRAPH * 256 * sizeof(float));
    float* cnt_g   = (float*)carve(NGRAPH * sizeof(float));

    hipMemsetAsync(cnt, 0, NN * sizeof(int), stream);
    hipMemsetAsync(fill, 0, NN * sizeof(int), stream);
    hipMemsetAsync(pool, 0, (size_t)NGRAPH * 256 * sizeof(float), stream);
    hipMemsetAsync(cnt_g, 0, NGRAPH * sizeof(float), stream);

    const int nblk = (NN + 255) / 256;  // 196

    // CSR build
    k_count<<<(NE + 255) / 256, 256, 0, stream>>>(dst, cnt);
    k_scan1<<<nblk, 256, 0, stream>>>(cnt, bsum);
    k_scan2<<<1, 256, 0, stream>>>(bsum, nblk);
    k_scan3<<<nblk, 256, 0, stream>>>(cnt, bsum, row_ptr, dinv);
    k_fill<<<(NEP + 255) / 256, 256, 0, stream>>>(src, dst, row_ptr, fill, colb);

    // GCN
    k_gemm64<<<(NN + 63) / 64, 256, 0, stream>>>(x, gcn_W, hx, NN);
    k_gcn_agg<<<(NN * 64 + 255) / 256, 256, 0, stream>>>(hx, row_ptr, colb, dinv, gcn_b, h);

    // GAT (gemm + fused attention logits, then single-pass online softmax agg)
    k_gemm256<<<(NN + 31) / 32, 256, 0, stream>>>(h, gat_W, att_src, att_dst, g, a_s, a_d);
    k_gat<<<NN / 4, 256, 0, stream>>>(g, a_s, a_d, row_ptr, colb, gat_b, batch, pool, cnt_g);

    // output projection
    k_out<<<(NGRAPH * NOUT + 255) / 256, 256, 0, stream>>>(pool, cnt_g, out_W, out_b, out);
}

// Round 5
// 379.257 us; speedup vs baseline: 1.7944x; 1.1334x over previous
//
#include <hip/hip_runtime.h>
#include <math.h>

#define NN 50000
#define NE 800000
#define NEP (NE + NN)   // edges incl self-loops
#define NGRAPH 500
#define NOUT 32

typedef _Float16 half4 __attribute__((ext_vector_type(4)));

// ---------------- CSR construction ----------------

__global__ void k_count(const int* __restrict__ dst, int* __restrict__ cnt) {
    int e = blockIdx.x * blockDim.x + threadIdx.x;
    if (e < NE) atomicAdd(&cnt[dst[e]], 1);
}

// pass 1: per-block sums of (cnt[i]+1)
__global__ __launch_bounds__(256) void k_scan1(const int* __restrict__ cnt, int* __restrict__ bsum) {
    __shared__ int buf[256];
    int i = blockIdx.x * 256 + threadIdx.x;
    int v = (i < NN) ? (cnt[i] + 1) : 0;
    buf[threadIdx.x] = v;
    __syncthreads();
    for (int off = 128; off; off >>= 1) {
        if (threadIdx.x < off) buf[threadIdx.x] += buf[threadIdx.x + off];
        __syncthreads();
    }
    if (threadIdx.x == 0) bsum[blockIdx.x] = buf[0];
}

// pass 2: exclusive scan of block sums (nblk <= 256), single block
__global__ __launch_bounds__(256) void k_scan2(int* __restrict__ bsum, int nblk) {
    __shared__ int buf[256];
    int tid = threadIdx.x;
    int v = (tid < nblk) ? bsum[tid] : 0;
    buf[tid] = v;
    __syncthreads();
    for (int off = 1; off < 256; off <<= 1) {
        int t = (tid >= off) ? buf[tid - off] : 0;
        __syncthreads();
        buf[tid] += t;
        __syncthreads();
    }
    if (tid < nblk) bsum[tid] = buf[tid] - v;  // exclusive
}

// pass 3: intra-block exclusive scan + block offset -> row_ptr; also dinv
__global__ __launch_bounds__(256) void k_scan3(const int* __restrict__ cnt,
                                               const int* __restrict__ bsum,
                                               int* __restrict__ row_ptr,
                                               float* __restrict__ dinv) {
    __shared__ int buf[256];
    int tid = threadIdx.x;
    int i = blockIdx.x * 256 + tid;
    int v = (i < NN) ? (cnt[i] + 1) : 0;
    buf[tid] = v;
    __syncthreads();
    for (int off = 1; off < 256; off <<= 1) {
        int t = (tid >= off) ? buf[tid - off] : 0;
        __syncthreads();
        buf[tid] += t;
        __syncthreads();
    }
    if (i < NN) {
        row_ptr[i] = bsum[blockIdx.x] + buf[tid] - v;
        dinv[i] = rsqrtf((float)(cnt[i] + 1));
    }
    if (i == NN - 1) row_ptr[NN] = bsum[blockIdx.x] + buf[tid];
}

__global__ void k_fill(const int* __restrict__ src, const int* __restrict__ dst,
                       const int* __restrict__ row_ptr, int* __restrict__ fill,
                       int* __restrict__ col) {
    int idx = blockIdx.x * blockDim.x + threadIdx.x;
    if (idx < NE) {
        int d = dst[idx];
        int p = row_ptr[d] + atomicAdd(&fill[d], 1);
        col[p] = src[idx];
    } else if (idx < NEP) {
        int i = idx - NE;
        int p = row_ptr[i] + atomicAdd(&fill[i], 1);
        col[p] = i;   // self loop
    }
}

// ---------------- GEMMs ----------------

// C[n x 64] = A[n x 64] @ B[64 x 64]; block=256, 64 rows/block.
__global__ __launch_bounds__(256) void k_gemm64(const float* __restrict__ A,
                                                const float* __restrict__ B,
                                                float* __restrict__ C, int n) {
    __shared__ float Bs[64 * 64];    // 16 KB
    __shared__ float As[64 * 68];    // 17 KB, stride 68
    int tid = threadIdx.x;
    int rb = blockIdx.x * 64;
    for (int i = tid; i < 1024; i += 256) ((float4*)Bs)[i] = ((const float4*)B)[i];
    for (int i = tid; i < 1024; i += 256) {
        int r = i >> 4, c = i & 15;
        int row = rb + r; if (row >= n) row = n - 1;
        ((float4*)As)[r * 17 + c] = ((const float4*)A)[(size_t)row * 16 + c];
    }
    __syncthreads();
    int lane = tid & 63, wv = tid >> 6;
    int fl = lane & 15, sub = lane >> 4;
    int r0 = wv * 16 + sub * 4;      // first of 4 rows (within tile)
    const float4* Bs4 = (const float4*)Bs;
    float4 acc0 = {0,0,0,0}, acc1 = {0,0,0,0}, acc2 = {0,0,0,0}, acc3 = {0,0,0,0};
#pragma unroll 4
    for (int k = 0; k < 64; ++k) {
        float4 b4 = Bs4[k * 16 + fl];
        float a0 = As[(r0 + 0) * 68 + k];
        float a1 = As[(r0 + 1) * 68 + k];
        float a2 = As[(r0 + 2) * 68 + k];
        float a3 = As[(r0 + 3) * 68 + k];
        acc0.x += a0 * b4.x; acc0.y += a0 * b4.y; acc0.z += a0 * b4.z; acc0.w += a0 * b4.w;
        acc1.x += a1 * b4.x; acc1.y += a1 * b4.y; acc1.z += a1 * b4.z; acc1.w += a1 * b4.w;
        acc2.x += a2 * b4.x; acc2.y += a2 * b4.y; acc2.z += a2 * b4.z; acc2.w += a2 * b4.w;
        acc3.x += a3 * b4.x; acc3.y += a3 * b4.y; acc3.z += a3 * b4.z; acc3.w += a3 * b4.w;
    }
    int row = rb + r0;
    if (row + 0 < n) ((float4*)(C + (size_t)(row + 0) * 64))[fl] = acc0;
    if (row + 1 < n) ((float4*)(C + (size_t)(row + 1) * 64))[fl] = acc1;
    if (row + 2 < n) ((float4*)(C + (size_t)(row + 2) * 64))[fl] = acc2;
    if (row + 3 < n) ((float4*)(C + (size_t)(row + 3) * 64))[fl] = acc3;
}

// g16[n x 256] (fp16) = h[n x 64] @ W[64 x 256] + fused attention logits (fp32).
// Block = 4 waves x 8 rows = 32 rows. Lane owns cols [4*lane, 4*lane+3].
__global__ __launch_bounds__(256) void k_gemm256(const float* __restrict__ A,
                                                 const float* __restrict__ B,
                                                 const float* __restrict__ att_src,
                                                 const float* __restrict__ att_dst,
                                                 _Float16* __restrict__ g16,
                                                 float* __restrict__ a_s,
                                                 float* __restrict__ a_d) {
    __shared__ float Bs[64 * 256];   // 64 KB
    __shared__ float As[32 * 64];    // 8 KB
    int tid = threadIdx.x;
    int rb = blockIdx.x * 32;
    for (int i = tid; i < 4096; i += 256) ((float4*)Bs)[i] = ((const float4*)B)[i];
    for (int i = tid; i < 512; i += 256) {
        int r = i >> 4, c = i & 15;
        int row = rb + r; if (row >= NN) row = NN - 1;
        ((float4*)As)[i] = ((const float4*)A)[(size_t)row * 16 + c];
    }
    __syncthreads();
    int lane = tid & 63, wv = tid >> 6;
    const float4* Bs4 = (const float4*)Bs;
    float4 as4 = ((const float4*)att_src)[lane];
    float4 ad4 = ((const float4*)att_dst)[lane];
    const float* Aw = As + (wv * 8) * 64;
    float4 acc[8];
#pragma unroll
    for (int r = 0; r < 8; ++r) acc[r] = make_float4(0.f, 0.f, 0.f, 0.f);
#pragma unroll 4
    for (int k = 0; k < 64; ++k) {
        float4 b4 = Bs4[k * 64 + lane];
#pragma unroll
        for (int r = 0; r < 8; ++r) {
            float av = Aw[r * 64 + k];
            acc[r].x += av * b4.x; acc[r].y += av * b4.y;
            acc[r].z += av * b4.z; acc[r].w += av * b4.w;
        }
    }
#pragma unroll
    for (int r = 0; r < 8; ++r) {
        int row = rb + wv * 8 + r;
        bool valid = row < NN;   // wave-uniform
        if (valid) {
            half4 hv;
            hv.x = (_Float16)acc[r].x; hv.y = (_Float16)acc[r].y;
            hv.z = (_Float16)acc[r].z; hv.w = (_Float16)acc[r].w;
            ((half4*)(g16 + (size_t)row * 256))[lane] = hv;
        }
        float vs = acc[r].x * as4.x + acc[r].y * as4.y + acc[r].z * as4.z + acc[r].w * as4.w;
        float vd = acc[r].x * ad4.x + acc[r].y * ad4.y + acc[r].z * ad4.z + acc[r].w * ad4.w;
#pragma unroll
        for (int off = 1; off < 16; off <<= 1) {
            vs += __shfl_xor(vs, off);
            vd += __shfl_xor(vd, off);
        }
        if (valid && (lane & 15) == 0) {
            a_s[row * 4 + (lane >> 4)] = vs;
            a_d[row * 4 + (lane >> 4)] = vd;
        }
    }
}

// ---------------- GCN aggregation: one wave/node, 8 edges in flight ----------------

__global__ __launch_bounds__(256) void k_gcn_agg(const float* __restrict__ hx,
                                                 const int* __restrict__ row_ptr,
                                                 const int* __restrict__ col,
                                                 const float* __restrict__ dinv,
                                                 const float* __restrict__ bias,
                                                 float* __restrict__ h) {
    int wid = (blockIdx.x * blockDim.x + threadIdx.x) >> 6;
    int lane = threadIdx.x & 63;
    if (wid >= NN) return;
    int sub = lane >> 4;    // edge slot within 4-group
    int fl  = lane & 15;    // float4 index within row
    int s0 = row_ptr[wid], s1 = row_ptr[wid + 1];
    float di = dinv[wid];
    const float4* hx4 = (const float4*)hx;
    float ax = 0.f, ay = 0.f, az = 0.f, aw = 0.f;
    int k = s0 + sub;
    for (; k + 4 < s1; k += 8) {
        int sA = col[k], sB = col[k + 4];
        float wA = dinv[sA] * di, wB = dinv[sB] * di;
        float4 vA = hx4[(size_t)sA * 16 + fl];
        float4 vB = hx4[(size_t)sB * 16 + fl];
        ax += wA * vA.x + wB * vB.x;
        ay += wA * vA.y + wB * vB.y;
        az += wA * vA.z + wB * vB.z;
        aw += wA * vA.w + wB * vB.w;
    }
    if (k < s1) {
        int s = col[k];
        float w = dinv[s] * di;
        float4 v = hx4[(size_t)s * 16 + fl];
        ax += w * v.x; ay += w * v.y; az += w * v.z; aw += w * v.w;
    }
    ax += __shfl_xor(ax, 16); ax += __shfl_xor(ax, 32);
    ay += __shfl_xor(ay, 16); ay += __shfl_xor(ay, 32);
    az += __shfl_xor(az, 16); az += __shfl_xor(az, 32);
    aw += __shfl_xor(aw, 16); aw += __shfl_xor(aw, 32);
    if (sub == 0) {
        float4 bb = ((const float4*)bias)[fl];
        float4 z;
        z.x = fmaxf(ax + bb.x, 0.f);
        z.y = fmaxf(ay + bb.y, 0.f);
        z.z = fmaxf(az + bb.z, 0.f);
        z.w = fmaxf(aw + bb.w, 0.f);
        ((float4*)(h + (size_t)wid * 64))[fl] = z;
    }
}

// ---------------- GAT: single-pass online softmax, fp16 value gather ----------------

__device__ __forceinline__ float lrelu(float x) { return x > 0.f ? x : 0.2f * x; }

__global__ __launch_bounds__(256) void k_gat(const _Float16* __restrict__ g16,
                                             const float* __restrict__ a_s,
                                             const float* __restrict__ a_d,
                                             const int* __restrict__ row_ptr,
                                             const int* __restrict__ col,
                                             const float* __restrict__ gat_b,
                                             const int* __restrict__ batch,
                                             float* __restrict__ pool,
                                             float* __restrict__ cnt_g) {
    __shared__ float zpool[256];
    __shared__ int bids[4];
    int tid = threadIdx.x;
    int wv = tid >> 6, lane = tid & 63;
    int wid = blockIdx.x * 4 + wv;           // NN == gridDim.x*4, always valid
    int hh = lane >> 4;                      // head owned by this lane

    int s0 = row_ptr[wid], s1 = row_ptr[wid + 1];
    float adsel = a_d[wid * 4 + hh];
    const half4* gv4 = (const half4*)g16;

    float m = -1e30f, t = 0.f;
    float ax = 0.f, ay = 0.f, az = 0.f, aw = 0.f;

    int k = s0;
    for (; k + 7 < s1; k += 8) {
        int i0 = col[k], i1 = col[k + 1], i2 = col[k + 2], i3 = col[k + 3];
        int i4 = col[k + 4], i5 = col[k + 5], i6 = col[k + 6], i7 = col[k + 7];
        float e0 = lrelu(a_s[i0 * 4 + hh] + adsel);
        float e1 = lrelu(a_s[i1 * 4 + hh] + adsel);
        float e2 = lrelu(a_s[i2 * 4 + hh] + adsel);
        float e3 = lrelu(a_s[i3 * 4 + hh] + adsel);
        float e4 = lrelu(a_s[i4 * 4 + hh] + adsel);
        float e5 = lrelu(a_s[i5 * 4 + hh] + adsel);
        float e6 = lrelu(a_s[i6 * 4 + hh] + adsel);
        float e7 = lrelu(a_s[i7 * 4 + hh] + adsel);
        half4 g0 = gv4[(size_t)i0 * 64 + lane];
        half4 g1 = gv4[(size_t)i1 * 64 + lane];
        half4 g2 = gv4[(size_t)i2 * 64 + lane];
        half4 g3 = gv4[(size_t)i3 * 64 + lane];
        half4 g4v = gv4[(size_t)i4 * 64 + lane];
        half4 g5v = gv4[(size_t)i5 * 64 + lane];
        half4 g6 = gv4[(size_t)i6 * 64 + lane];
        half4 g7 = gv4[(size_t)i7 * 64 + lane];
        float mn = fmaxf(fmaxf(fmaxf(e0, e1), fmaxf(e2, e3)),
                         fmaxf(fmaxf(e4, e5), fmaxf(e6, e7)));
        mn = fmaxf(mn, m);
        float c = __expf(m - mn);
        float w0 = __expf(e0 - mn), w1 = __expf(e1 - mn);
        float w2 = __expf(e2 - mn), w3 = __expf(e3 - mn);
        float w4 = __expf(e4 - mn), w5 = __expf(e5 - mn);
        float w6 = __expf(e6 - mn), w7 = __expf(e7 - mn);
        t = t * c + ((w0 + w1) + (w2 + w3)) + ((w4 + w5) + (w6 + w7));
        ax = ax * c + w0 * (float)g0.x + w1 * (float)g1.x + w2 * (float)g2.x + w3 * (float)g3.x
                    + w4 * (float)g4v.x + w5 * (float)g5v.x + w6 * (float)g6.x + w7 * (float)g7.x;
        ay = ay * c + w0 * (float)g0.y + w1 * (float)g1.y + w2 * (float)g2.y + w3 * (float)g3.y
                    + w4 * (float)g4v.y + w5 * (float)g5v.y + w6 * (float)g6.y + w7 * (float)g7.y;
        az = az * c + w0 * (float)g0.z + w1 * (float)g1.z + w2 * (float)g2.z + w3 * (float)g3.z
                    + w4 * (float)g4v.z + w5 * (float)g5v.z + w6 * (float)g6.z + w7 * (float)g7.z;
        aw = aw * c + w0 * (float)g0.w + w1 * (float)g1.w + w2 * (float)g2.w + w3 * (float)g3.w
                    + w4 * (float)g4v.w + w5 * (float)g5v.w + w6 * (float)g6.w + w7 * (float)g7.w;
        m = mn;
    }
    for (; k + 3 < s1; k += 4) {
        int i0 = col[k], i1 = col[k + 1], i2 = col[k + 2], i3 = col[k + 3];
        float e0 = lrelu(a_s[i0 * 4 + hh] + adsel);
        float e1 = lrelu(a_s[i1 * 4 + hh] + adsel);
        float e2 = lrelu(a_s[i2 * 4 + hh] + adsel);
        float e3 = lrelu(a_s[i3 * 4 + hh] + adsel);
        half4 g0 = gv4[(size_t)i0 * 64 + lane];
        half4 g1 = gv4[(size_t)i1 * 64 + lane];
        half4 g2 = gv4[(size_t)i2 * 64 + lane];
        half4 g3 = gv4[(size_t)i3 * 64 + lane];
        float mn = fmaxf(fmaxf(fmaxf(e0, e1), fmaxf(e2, e3)), m);
        float c = __expf(m - mn);
        float w0 = __expf(e0 - mn), w1 = __expf(e1 - mn);
        float w2 = __expf(e2 - mn), w3 = __expf(e3 - mn);
        t = t * c + (w0 + w1) + (w2 + w3);
        ax = ax * c + w0 * (float)g0.x + w1 * (float)g1.x + w2 * (float)g2.x + w3 * (float)g3.x;
        ay = ay * c + w0 * (float)g0.y + w1 * (float)g1.y + w2 * (float)g2.y + w3 * (float)g3.y;
        az = az * c + w0 * (float)g0.z + w1 * (float)g1.z + w2 * (float)g2.z + w3 * (float)g3.z;
        aw = aw * c + w0 * (float)g0.w + w1 * (float)g1.w + w2 * (float)g2.w + w3 * (float)g3.w;
        m = mn;
    }
    for (; k < s1; ++k) {
        int s = col[k];
        float e = lrelu(a_s[s * 4 + hh] + adsel);
        half4 gv = gv4[(size_t)s * 64 + lane];
        float mn = fmaxf(m, e);
        float c = __expf(m - mn);
        float w = __expf(e - mn);
        t = t * c + w;
        ax = ax * c + w * (float)gv.x;
        ay = ay * c + w * (float)gv.y;
        az = az * c + w * (float)gv.z;
        aw = aw * c + w * (float)gv.w;
        m = mn;
    }
    float r = 1.f / t;

    float4 gb = ((const float4*)gat_b)[lane];
    float zx = fmaxf(ax * r + gb.x, 0.f);
    float zy = fmaxf(ay * r + gb.y, 0.f);
    float zz = fmaxf(az * r + gb.z, 0.f);
    float zw = fmaxf(aw * r + gb.w, 0.f);

    int b = batch[wid];
    if (lane == 0) bids[wv] = b;
    zpool[tid] = 0.f;
    __syncthreads();
    bool uni = (bids[0] == bids[1]) && (bids[1] == bids[2]) && (bids[2] == bids[3]);
    if (uni) {
        atomicAdd(&zpool[lane * 4 + 0], zx);
        atomicAdd(&zpool[lane * 4 + 1], zy);
        atomicAdd(&zpool[lane * 4 + 2], zz);
        atomicAdd(&zpool[lane * 4 + 3], zw);
        __syncthreads();
        if (wv == 0) {
            float* p = pool + (size_t)bids[0] * 256;
            atomicAdd(&p[lane * 4 + 0], zpool[lane * 4 + 0]);
            atomicAdd(&p[lane * 4 + 1], zpool[lane * 4 + 1]);
            atomicAdd(&p[lane * 4 + 2], zpool[lane * 4 + 2]);
            atomicAdd(&p[lane * 4 + 3], zpool[lane * 4 + 3]);
        }
        if (tid == 0) atomicAdd(&cnt_g[bids[0]], 4.0f);
    } else {
        __syncthreads();
        float* p = pool + (size_t)b * 256;
        atomicAdd(&p[lane * 4 + 0], zx);
        atomicAdd(&p[lane * 4 + 1], zy);
        atomicAdd(&p[lane * 4 + 2], zz);
        atomicAdd(&p[lane * 4 + 3], zw);
        if (lane == 0) atomicAdd(&cnt_g[b], 1.0f);
    }
}

// ---------------- output projection ----------------

__global__ void k_out(const float* __restrict__ pool, const float* __restrict__ cnt_g,
                      const float* __restrict__ W, const float* __restrict__ b,
                      float* __restrict__ out) {
    int idx = blockIdx.x * blockDim.x + threadIdx.x;
    if (idx >= NGRAPH * NOUT) return;
    int gg = idx >> 5, o = idx & 31;
    float c = cnt_g[gg];
    c = c > 1.f ? c : 1.f;
    float rinv = 1.f / c;
    const float* p = pool + (size_t)gg * 256;
    float acc = 0.f;
#pragma unroll 8
    for (int f = 0; f < 256; ++f) acc += p[f] * W[f * 32 + o];
    out[idx] = acc * rinv + b[o];
}

// ---------------- launch ----------------

extern "C" void kernel_launch(void* const* d_in, const int* in_sizes, int n_in,
                              void* d_out, int out_size, void* d_ws, size_t ws_size,
                              hipStream_t stream) {
    const float* x       = (const float*)d_in[0];
    const int*   eidx    = (const int*)d_in[1];
    const int*   batch   = (const int*)d_in[2];
    const float* gcn_W   = (const float*)d_in[3];
    const float* gcn_b   = (const float*)d_in[4];
    const float* gat_W   = (const float*)d_in[5];
    const float* att_src = (const float*)d_in[6];
    const float* att_dst = (const float*)d_in[7];
    const float* gat_b   = (const float*)d_in[8];
    const float* out_W   = (const float*)d_in[9];
    const float* out_b   = (const float*)d_in[10];
    float* out = (float*)d_out;

    const int* src = eidx;        // edge_index[0]
    const int* dst = eidx + NE;   // edge_index[1]

    size_t off = 0;
    auto carve = [&](size_t bytes) -> char* {
        char* p = (char*)d_ws + off;
        off += (bytes + 255) & ~(size_t)255;
        return p;
    };
    int*      cnt     = (int*)carve(NN * sizeof(int));
    int*      fill    = (int*)carve(NN * sizeof(int));
    int*      row_ptr = (int*)carve((NN + 1) * sizeof(int));
    int*      bsum    = (int*)carve(256 * sizeof(int));
    int*      colb    = (int*)carve((size_t)NEP * sizeof(int));
    float*    dinv    = (float*)carve(NN * sizeof(float));
    float*    hx      = (float*)carve((size_t)NN * 64 * sizeof(float));
    float*    h       = (float*)carve((size_t)NN * 64 * sizeof(float));
    _Float16* g16     = (_Float16*)carve((size_t)NN * 256 * sizeof(_Float16));
    float*    a_s     = (float*)carve((size_t)NN * 4 * sizeof(float));
    float*    a_d     = (float*)carve((size_t)NN * 4 * sizeof(float));
    float*    pool    = (float*)carve((size_t)NGRAPH * 256 * sizeof(float));
    float*    cnt_g   = (float*)carve(NGRAPH * sizeof(float));

    hipMemsetAsync(cnt, 0, NN * sizeof(int), stream);
    hipMemsetAsync(fill, 0, NN * sizeof(int), stream);
    hipMemsetAsync(pool, 0, (size_t)NGRAPH * 256 * sizeof(float), stream);
    hipMemsetAsync(cnt_g, 0, NGRAPH * sizeof(float), stream);

    const int nblk = (NN + 255) / 256;  // 196

    // CSR build
    k_count<<<(NE + 255) / 256, 256, 0, stream>>>(dst, cnt);
    k_scan1<<<nblk, 256, 0, stream>>>(cnt, bsum);
    k_scan2<<<1, 256, 0, stream>>>(bsum, nblk);
    k_scan3<<<nblk, 256, 0, stream>>>(cnt, bsum, row_ptr, dinv);
    k_fill<<<(NEP + 255) / 256, 256, 0, stream>>>(src, dst, row_ptr, fill, colb);

    // GCN
    k_gemm64<<<(NN + 63) / 64, 256, 0, stream>>>(x, gcn_W, hx, NN);
    k_gcn_agg<<<(NN * 64 + 255) / 256, 256, 0, stream>>>(hx, row_ptr, colb, dinv, gcn_b, h);

    // GAT (gemm + fused logits -> fp16 g, then single-pass online softmax agg)
    k_gemm256<<<(NN + 31) / 32, 256, 0, stream>>>(h, gat_W, att_src, att_dst, g16, a_s, a_d);
    k_gat<<<NN / 4, 256, 0, stream>>>(g16, a_s, a_d, row_ptr, colb, gat_b, batch, pool, cnt_g);

    // output projection
    k_out<<<(NGRAPH * NOUT + 255) / 256, 256, 0, stream>>>(pool, cnt_g, out_W, out_b, out);
}

// Round 6
// 368.022 us; speedup vs baseline: 1.8492x; 1.0305x over previous
//
#include <hip/hip_runtime.h>
#include <math.h>

#define NN 50000
#define NE 800000
#define NEP (NE + NN)   // edges incl self-loops
#define NGRAPH 500
#define NOUT 32
#define NBLK 196        // ceil(NN/256)

typedef _Float16 half4 __attribute__((ext_vector_type(4)));

// ---------------- CSR construction ----------------

__global__ void k_count(const int* __restrict__ dst, int* __restrict__ cnt) {
    int e = blockIdx.x * blockDim.x + threadIdx.x;
    if (e < NE) atomicAdd(&cnt[dst[e]], 1);
}

// pass 1: per-block sums of (cnt[i]+1); also zero pool & cnt_g (pre-k_gat)
__global__ __launch_bounds__(256) void k_scan1(const int* __restrict__ cnt, int* __restrict__ bsum,
                                               float* __restrict__ pool, float* __restrict__ cnt_g) {
    __shared__ int buf[256];
    int gid = blockIdx.x * 256 + threadIdx.x;
    int v = (gid < NN) ? (cnt[gid] + 1) : 0;
    buf[threadIdx.x] = v;
    for (int j = gid; j < NGRAPH * 256; j += NBLK * 256) pool[j] = 0.f;
    if (gid < NGRAPH) cnt_g[gid] = 0.f;
    __syncthreads();
    for (int off = 128; off; off >>= 1) {
        if (threadIdx.x < off) buf[threadIdx.x] += buf[threadIdx.x + off];
        __syncthreads();
    }
    if (threadIdx.x == 0) bsum[blockIdx.x] = buf[0];
}

// pass 2 (fused): every block scans the 196 block sums redundantly, then does
// its intra-block exclusive scan -> row_ptr; also dinv and fill-zeroing.
__global__ __launch_bounds__(256) void k_scan3(const int* __restrict__ cnt,
                                               const int* __restrict__ bsum,
                                               int* __restrict__ row_ptr,
                                               float* __restrict__ dinv,
                                               int* __restrict__ fill) {
    __shared__ int sb[256];
    __shared__ int buf[256];
    int tid = threadIdx.x;
    // inclusive scan of bsum (196 entries)
    int bv = (tid < NBLK) ? bsum[tid] : 0;
    sb[tid] = bv;
    __syncthreads();
    for (int off = 1; off < 256; off <<= 1) {
        int t = (tid >= off) ? sb[tid - off] : 0;
        __syncthreads();
        sb[tid] += t;
        __syncthreads();
    }
    int blockoff = (blockIdx.x == 0) ? 0 : sb[blockIdx.x - 1];
    // intra-block scan of cnt+1
    int i = blockIdx.x * 256 + tid;
    int v = (i < NN) ? (cnt[i] + 1) : 0;
    buf[tid] = v;
    __syncthreads();
    for (int off = 1; off < 256; off <<= 1) {
        int t = (tid >= off) ? buf[tid - off] : 0;
        __syncthreads();
        buf[tid] += t;
        __syncthreads();
    }
    if (i < NN) {
        row_ptr[i] = blockoff + buf[tid] - v;
        dinv[i] = rsqrtf((float)(cnt[i] + 1));
        fill[i] = 0;
    }
    if (i == 0) row_ptr[NN] = NEP;
}

__global__ void k_fill(const int* __restrict__ src, const int* __restrict__ dst,
                       const int* __restrict__ row_ptr, int* __restrict__ fill,
                       int* __restrict__ col) {
    int idx = blockIdx.x * blockDim.x + threadIdx.x;
    if (idx < NE) {
        int d = dst[idx];
        int p = row_ptr[d] + atomicAdd(&fill[d], 1);
        col[p] = src[idx];
    } else if (idx < NEP) {
        int i = idx - NE;
        int p = row_ptr[i] + atomicAdd(&fill[i], 1);
        col[p] = i;   // self loop
    }
}

// ---------------- GEMMs ----------------

// hx16[n x 64] (fp16) = x[n x 64] @ W[64 x 64]; block=256, 64 rows/block.
__global__ __launch_bounds__(256) void k_gemm64(const float* __restrict__ A,
                                                const float* __restrict__ B,
                                                _Float16* __restrict__ C16, int n) {
    __shared__ float Bs[64 * 64];    // 16 KB
    __shared__ float As[64 * 68];    // 17 KB, stride 68
    int tid = threadIdx.x;
    int rb = blockIdx.x * 64;
    for (int i = tid; i < 1024; i += 256) ((float4*)Bs)[i] = ((const float4*)B)[i];
    for (int i = tid; i < 1024; i += 256) {
        int r = i >> 4, c = i & 15;
        int row = rb + r; if (row >= n) row = n - 1;
        ((float4*)As)[r * 17 + c] = ((const float4*)A)[(size_t)row * 16 + c];
    }
    __syncthreads();
    int lane = tid & 63, wv = tid >> 6;
    int fl = lane & 15, sub = lane >> 4;
    int r0 = wv * 16 + sub * 4;
    const float4* Bs4 = (const float4*)Bs;
    float4 acc0 = {0,0,0,0}, acc1 = {0,0,0,0}, acc2 = {0,0,0,0}, acc3 = {0,0,0,0};
#pragma unroll 4
    for (int k = 0; k < 64; ++k) {
        float4 b4 = Bs4[k * 16 + fl];
        float a0 = As[(r0 + 0) * 68 + k];
        float a1 = As[(r0 + 1) * 68 + k];
        float a2 = As[(r0 + 2) * 68 + k];
        float a3 = As[(r0 + 3) * 68 + k];
        acc0.x += a0 * b4.x; acc0.y += a0 * b4.y; acc0.z += a0 * b4.z; acc0.w += a0 * b4.w;
        acc1.x += a1 * b4.x; acc1.y += a1 * b4.y; acc1.z += a1 * b4.z; acc1.w += a1 * b4.w;
        acc2.x += a2 * b4.x; acc2.y += a2 * b4.y; acc2.z += a2 * b4.z; acc2.w += a2 * b4.w;
        acc3.x += a3 * b4.x; acc3.y += a3 * b4.y; acc3.z += a3 * b4.z; acc3.w += a3 * b4.w;
    }
    int row = rb + r0;
    half4 h0, h1, h2, h3;
    h0.x=(_Float16)acc0.x; h0.y=(_Float16)acc0.y; h0.z=(_Float16)acc0.z; h0.w=(_Float16)acc0.w;
    h1.x=(_Float16)acc1.x; h1.y=(_Float16)acc1.y; h1.z=(_Float16)acc1.z; h1.w=(_Float16)acc1.w;
    h2.x=(_Float16)acc2.x; h2.y=(_Float16)acc2.y; h2.z=(_Float16)acc2.z; h2.w=(_Float16)acc2.w;
    h3.x=(_Float16)acc3.x; h3.y=(_Float16)acc3.y; h3.z=(_Float16)acc3.z; h3.w=(_Float16)acc3.w;
    if (row + 0 < n) ((half4*)(C16 + (size_t)(row + 0) * 64))[fl] = h0;
    if (row + 1 < n) ((half4*)(C16 + (size_t)(row + 1) * 64))[fl] = h1;
    if (row + 2 < n) ((half4*)(C16 + (size_t)(row + 2) * 64))[fl] = h2;
    if (row + 3 < n) ((half4*)(C16 + (size_t)(row + 3) * 64))[fl] = h3;
}

// g16[n x 256] (fp16) = h[n x 64] @ W[64 x 256] + fused attention logits (fp32).
__global__ __launch_bounds__(256) void k_gemm256(const float* __restrict__ A,
                                                 const float* __restrict__ B,
                                                 const float* __restrict__ att_src,
                                                 const float* __restrict__ att_dst,
                                                 _Float16* __restrict__ g16,
                                                 float* __restrict__ a_s,
                                                 float* __restrict__ a_d) {
    __shared__ float Bs[64 * 256];   // 64 KB
    __shared__ float As[32 * 64];    // 8 KB
    int tid = threadIdx.x;
    int rb = blockIdx.x * 32;
    for (int i = tid; i < 4096; i += 256) ((float4*)Bs)[i] = ((const float4*)B)[i];
    for (int i = tid; i < 512; i += 256) {
        int r = i >> 4, c = i & 15;
        int row = rb + r; if (row >= NN) row = NN - 1;
        ((float4*)As)[i] = ((const float4*)A)[(size_t)row * 16 + c];
    }
    __syncthreads();
    int lane = tid & 63, wv = tid >> 6;
    const float4* Bs4 = (const float4*)Bs;
    float4 as4 = ((const float4*)att_src)[lane];
    float4 ad4 = ((const float4*)att_dst)[lane];
    const float* Aw = As + (wv * 8) * 64;
    float4 acc[8];
#pragma unroll
    for (int r = 0; r < 8; ++r) acc[r] = make_float4(0.f, 0.f, 0.f, 0.f);
#pragma unroll 4
    for (int k = 0; k < 64; ++k) {
        float4 b4 = Bs4[k * 64 + lane];
#pragma unroll
        for (int r = 0; r < 8; ++r) {
            float av = Aw[r * 64 + k];
            acc[r].x += av * b4.x; acc[r].y += av * b4.y;
            acc[r].z += av * b4.z; acc[r].w += av * b4.w;
        }
    }
#pragma unroll
    for (int r = 0; r < 8; ++r) {
        int row = rb + wv * 8 + r;
        bool valid = row < NN;   // wave-uniform
        if (valid) {
            half4 hv;
            hv.x = (_Float16)acc[r].x; hv.y = (_Float16)acc[r].y;
            hv.z = (_Float16)acc[r].z; hv.w = (_Float16)acc[r].w;
            ((half4*)(g16 + (size_t)row * 256))[lane] = hv;
        }
        float vs = acc[r].x * as4.x + acc[r].y * as4.y + acc[r].z * as4.z + acc[r].w * as4.w;
        float vd = acc[r].x * ad4.x + acc[r].y * ad4.y + acc[r].z * ad4.z + acc[r].w * ad4.w;
#pragma unroll
        for (int off = 1; off < 16; off <<= 1) {
            vs += __shfl_xor(vs, off);
            vd += __shfl_xor(vd, off);
        }
        if (valid && (lane & 15) == 0) {
            a_s[row * 4 + (lane >> 4)] = vs;
            a_d[row * 4 + (lane >> 4)] = vd;
        }
    }
}

// ---------------- GCN aggregation: one wave/node, fp16 gather, 8 edges in flight ----------------

__global__ __launch_bounds__(256) void k_gcn_agg(const _Float16* __restrict__ hx16,
                                                 const int* __restrict__ row_ptr,
                                                 const int* __restrict__ col,
                                                 const float* __restrict__ dinv,
                                                 const float* __restrict__ bias,
                                                 float* __restrict__ h) {
    int wid = (blockIdx.x * blockDim.x + threadIdx.x) >> 6;
    int lane = threadIdx.x & 63;
    if (wid >= NN) return;
    int sub = lane >> 4;    // edge slot within 4-group
    int fl  = lane & 15;    // half4 index within row (16 * 8B = 64 halfs)
    int s0 = row_ptr[wid], s1 = row_ptr[wid + 1];
    float di = dinv[wid];
    const half4* hx4 = (const half4*)hx16;
    float ax = 0.f, ay = 0.f, az = 0.f, aw = 0.f;
    int k = s0 + sub;
    for (; k + 4 < s1; k += 8) {
        int sA = col[k], sB = col[k + 4];
        float wA = dinv[sA] * di, wB = dinv[sB] * di;
        half4 vA = hx4[(size_t)sA * 16 + fl];
        half4 vB = hx4[(size_t)sB * 16 + fl];
        ax += wA * (float)vA.x + wB * (float)vB.x;
        ay += wA * (float)vA.y + wB * (float)vB.y;
        az += wA * (float)vA.z + wB * (float)vB.z;
        aw += wA * (float)vA.w + wB * (float)vB.w;
    }
    if (k < s1) {
        int s = col[k];
        float w = dinv[s] * di;
        half4 v = hx4[(size_t)s * 16 + fl];
        ax += w * (float)v.x; ay += w * (float)v.y;
        az += w * (float)v.z; aw += w * (float)v.w;
    }
    ax += __shfl_xor(ax, 16); ax += __shfl_xor(ax, 32);
    ay += __shfl_xor(ay, 16); ay += __shfl_xor(ay, 32);
    az += __shfl_xor(az, 16); az += __shfl_xor(az, 32);
    aw += __shfl_xor(aw, 16); aw += __shfl_xor(aw, 32);
    if (sub == 0) {
        float4 bb = ((const float4*)bias)[fl];
        float4 z;
        z.x = fmaxf(ax + bb.x, 0.f);
        z.y = fmaxf(ay + bb.y, 0.f);
        z.z = fmaxf(az + bb.z, 0.f);
        z.w = fmaxf(aw + bb.w, 0.f);
        ((float4*)(h + (size_t)wid * 64))[fl] = z;
    }
}

// ---------------- GAT: single-pass online softmax, fp16 value gather ----------------

__device__ __forceinline__ float lrelu(float x) { return x > 0.f ? x : 0.2f * x; }

__global__ __launch_bounds__(256) void k_gat(const _Float16* __restrict__ g16,
                                             const float* __restrict__ a_s,
                                             const float* __restrict__ a_d,
                                             const int* __restrict__ row_ptr,
                                             const int* __restrict__ col,
                                             const float* __restrict__ gat_b,
                                             const int* __restrict__ batch,
                                             float* __restrict__ pool,
                                             float* __restrict__ cnt_g) {
    __shared__ float zpool[256];
    __shared__ int bids[4];
    int tid = threadIdx.x;
    int wv = tid >> 6, lane = tid & 63;
    int wid = blockIdx.x * 4 + wv;           // NN == gridDim.x*4, always valid
    int hh = lane >> 4;                      // head owned by this lane

    int s0 = row_ptr[wid], s1 = row_ptr[wid + 1];
    float adsel = a_d[wid * 4 + hh];
    const half4* gv4 = (const half4*)g16;

    float m = -1e30f, t = 0.f;
    float ax = 0.f, ay = 0.f, az = 0.f, aw = 0.f;

    int k = s0;
    for (; k + 7 < s1; k += 8) {
        int i0 = col[k], i1 = col[k + 1], i2 = col[k + 2], i3 = col[k + 3];
        int i4 = col[k + 4], i5 = col[k + 5], i6 = col[k + 6], i7 = col[k + 7];
        float e0 = lrelu(a_s[i0 * 4 + hh] + adsel);
        float e1 = lrelu(a_s[i1 * 4 + hh] + adsel);
        float e2 = lrelu(a_s[i2 * 4 + hh] + adsel);
        float e3 = lrelu(a_s[i3 * 4 + hh] + adsel);
        float e4 = lrelu(a_s[i4 * 4 + hh] + adsel);
        float e5 = lrelu(a_s[i5 * 4 + hh] + adsel);
        float e6 = lrelu(a_s[i6 * 4 + hh] + adsel);
        float e7 = lrelu(a_s[i7 * 4 + hh] + adsel);
        half4 g0 = gv4[(size_t)i0 * 64 + lane];
        half4 g1 = gv4[(size_t)i1 * 64 + lane];
        half4 g2 = gv4[(size_t)i2 * 64 + lane];
        half4 g3 = gv4[(size_t)i3 * 64 + lane];
        half4 g4v = gv4[(size_t)i4 * 64 + lane];
        half4 g5v = gv4[(size_t)i5 * 64 + lane];
        half4 g6 = gv4[(size_t)i6 * 64 + lane];
        half4 g7 = gv4[(size_t)i7 * 64 + lane];
        float mn = fmaxf(fmaxf(fmaxf(e0, e1), fmaxf(e2, e3)),
                         fmaxf(fmaxf(e4, e5), fmaxf(e6, e7)));
        mn = fmaxf(mn, m);
        float c = __expf(m - mn);
        float w0 = __expf(e0 - mn), w1 = __expf(e1 - mn);
        float w2 = __expf(e2 - mn), w3 = __expf(e3 - mn);
        float w4 = __expf(e4 - mn), w5 = __expf(e5 - mn);
        float w6 = __expf(e6 - mn), w7 = __expf(e7 - mn);
        t = t * c + ((w0 + w1) + (w2 + w3)) + ((w4 + w5) + (w6 + w7));
        ax = ax * c + w0 * (float)g0.x + w1 * (float)g1.x + w2 * (float)g2.x + w3 * (float)g3.x
                    + w4 * (float)g4v.x + w5 * (float)g5v.x + w6 * (float)g6.x + w7 * (float)g7.x;
        ay = ay * c + w0 * (float)g0.y + w1 * (float)g1.y + w2 * (float)g2.y + w3 * (float)g3.y
                    + w4 * (float)g4v.y + w5 * (float)g5v.y + w6 * (float)g6.y + w7 * (float)g7.y;
        az = az * c + w0 * (float)g0.z + w1 * (float)g1.z + w2 * (float)g2.z + w3 * (float)g3.z
                    + w4 * (float)g4v.z + w5 * (float)g5v.z + w6 * (float)g6.z + w7 * (float)g7.z;
        aw = aw * c + w0 * (float)g0.w + w1 * (float)g1.w + w2 * (float)g2.w + w3 * (float)g3.w
                    + w4 * (float)g4v.w + w5 * (float)g5v.w + w6 * (float)g6.w + w7 * (float)g7.w;
        m = mn;
    }
    for (; k + 3 < s1; k += 4) {
        int i0 = col[k], i1 = col[k + 1], i2 = col[k + 2], i3 = col[k + 3];
        float e0 = lrelu(a_s[i0 * 4 + hh] + adsel);
        float e1 = lrelu(a_s[i1 * 4 + hh] + adsel);
        float e2 = lrelu(a_s[i2 * 4 + hh] + adsel);
        float e3 = lrelu(a_s[i3 * 4 + hh] + adsel);
        half4 g0 = gv4[(size_t)i0 * 64 + lane];
        half4 g1 = gv4[(size_t)i1 * 64 + lane];
        half4 g2 = gv4[(size_t)i2 * 64 + lane];
        half4 g3 = gv4[(size_t)i3 * 64 + lane];
        float mn = fmaxf(fmaxf(fmaxf(e0, e1), fmaxf(e2, e3)), m);
        float c = __expf(m - mn);
        float w0 = __expf(e0 - mn), w1 = __expf(e1 - mn);
        float w2 = __expf(e2 - mn), w3 = __expf(e3 - mn);
        t = t * c + (w0 + w1) + (w2 + w3);
        ax = ax * c + w0 * (float)g0.x + w1 * (float)g1.x + w2 * (float)g2.x + w3 * (float)g3.x;
        ay = ay * c + w0 * (float)g0.y + w1 * (float)g1.y + w2 * (float)g2.y + w3 * (float)g3.y;
        az = az * c + w0 * (float)g0.z + w1 * (float)g1.z + w2 * (float)g2.z + w3 * (float)g3.z;
        aw = aw * c + w0 * (float)g0.w + w1 * (float)g1.w + w2 * (float)g2.w + w3 * (float)g3.w;
        m = mn;
    }
    for (; k < s1; ++k) {
        int s = col[k];
        float e = lrelu(a_s[s * 4 + hh] + adsel);
        half4 gv = gv4[(size_t)s * 64 + lane];
        float mn = fmaxf(m, e);
        float c = __expf(m - mn);
        float w = __expf(e - mn);
        t = t * c + w;
        ax = ax * c + w * (float)gv.x;
        ay = ay * c + w * (float)gv.y;
        az = az * c + w * (float)gv.z;
        aw = aw * c + w * (float)gv.w;
        m = mn;
    }
    float r = 1.f / t;

    float4 gb = ((const float4*)gat_b)[lane];
    float zx = fmaxf(ax * r + gb.x, 0.f);
    float zy = fmaxf(ay * r + gb.y, 0.f);
    float zz = fmaxf(az * r + gb.z, 0.f);
    float zw = fmaxf(aw * r + gb.w, 0.f);

    int b = batch[wid];
    if (lane == 0) bids[wv] = b;
    zpool[tid] = 0.f;
    __syncthreads();
    bool uni = (bids[0] == bids[1]) && (bids[1] == bids[2]) && (bids[2] == bids[3]);
    if (uni) {
        atomicAdd(&zpool[lane * 4 + 0], zx);
        atomicAdd(&zpool[lane * 4 + 1], zy);
        atomicAdd(&zpool[lane * 4 + 2], zz);
        atomicAdd(&zpool[lane * 4 + 3], zw);
        __syncthreads();
        if (wv == 0) {
            float* p = pool + (size_t)bids[0] * 256;
            atomicAdd(&p[lane * 4 + 0], zpool[lane * 4 + 0]);
            atomicAdd(&p[lane * 4 + 1], zpool[lane * 4 + 1]);
            atomicAdd(&p[lane * 4 + 2], zpool[lane * 4 + 2]);
            atomicAdd(&p[lane * 4 + 3], zpool[lane * 4 + 3]);
        }
        if (tid == 0) atomicAdd(&cnt_g[bids[0]], 4.0f);
    } else {
        __syncthreads();
        float* p = pool + (size_t)b * 256;
        atomicAdd(&p[lane * 4 + 0], zx);
        atomicAdd(&p[lane * 4 + 1], zy);
        atomicAdd(&p[lane * 4 + 2], zz);
        atomicAdd(&p[lane * 4 + 3], zw);
        if (lane == 0) atomicAdd(&cnt_g[b], 1.0f);
    }
}

// ---------------- output projection ----------------

__global__ void k_out(const float* __restrict__ pool, const float* __restrict__ cnt_g,
                      const float* __restrict__ W, const float* __restrict__ b,
                      float* __restrict__ out) {
    int idx = blockIdx.x * blockDim.x + threadIdx.x;
    if (idx >= NGRAPH * NOUT) return;
    int gg = idx >> 5, o = idx & 31;
    float c = cnt_g[gg];
    c = c > 1.f ? c : 1.f;
    float rinv = 1.f / c;
    const float* p = pool + (size_t)gg * 256;
    float acc = 0.f;
#pragma unroll 8
    for (int f = 0; f < 256; ++f) acc += p[f] * W[f * 32 + o];
    out[idx] = acc * rinv + b[o];
}

// ---------------- launch ----------------

extern "C" void kernel_launch(void* const* d_in, const int* in_sizes, int n_in,
                              void* d_out, int out_size, void* d_ws, size_t ws_size,
                              hipStream_t stream) {
    const float* x       = (const float*)d_in[0];
    const int*   eidx    = (const int*)d_in[1];
    const int*   batch   = (const int*)d_in[2];
    const float* gcn_W   = (const float*)d_in[3];
    const float* gcn_b   = (const float*)d_in[4];
    const float* gat_W   = (const float*)d_in[5];
    const float* att_src = (const float*)d_in[6];
    const float* att_dst = (const float*)d_in[7];
    const float* gat_b   = (const float*)d_in[8];
    const float* out_W   = (const float*)d_in[9];
    const float* out_b   = (const float*)d_in[10];
    float* out = (float*)d_out;

    const int* src = eidx;        // edge_index[0]
    const int* dst = eidx + NE;   // edge_index[1]

    size_t off = 0;
    auto carve = [&](size_t bytes) -> char* {
        char* p = (char*)d_ws + off;
        off += (bytes + 255) & ~(size_t)255;
        return p;
    };
    int*      cnt     = (int*)carve(NN * sizeof(int));
    int*      fill    = (int*)carve(NN * sizeof(int));
    int*      row_ptr = (int*)carve((NN + 1) * sizeof(int));
    int*      bsum    = (int*)carve(256 * sizeof(int));
    int*      colb    = (int*)carve((size_t)NEP * sizeof(int));
    float*    dinv    = (float*)carve(NN * sizeof(float));
    _Float16* hx16    = (_Float16*)carve((size_t)NN * 64 * sizeof(_Float16));
    float*    h       = (float*)carve((size_t)NN * 64 * sizeof(float));
    _Float16* g16     = (_Float16*)carve((size_t)NN * 256 * sizeof(_Float16));
    float*    a_s     = (float*)carve((size_t)NN * 4 * sizeof(float));
    float*    a_d     = (float*)carve((size_t)NN * 4 * sizeof(float));
    float*    pool    = (float*)carve((size_t)NGRAPH * 256 * sizeof(float));
    float*    cnt_g   = (float*)carve(NGRAPH * sizeof(float));

    hipMemsetAsync(cnt, 0, NN * sizeof(int), stream);

    // CSR build (scan2 folded into scan3; fill/pool/cnt_g zeroing folded in)
    k_count<<<(NE + 255) / 256, 256, 0, stream>>>(dst, cnt);
    k_scan1<<<NBLK, 256, 0, stream>>>(cnt, bsum, pool, cnt_g);
    k_scan3<<<NBLK, 256, 0, stream>>>(cnt, bsum, row_ptr, dinv, fill);
    k_fill<<<(NEP + 255) / 256, 256, 0, stream>>>(src, dst, row_ptr, fill, colb);

    // GCN
    k_gemm64<<<(NN + 63) / 64, 256, 0, stream>>>(x, gcn_W, hx16, NN);
    k_gcn_agg<<<(NN * 64 + 255) / 256, 256, 0, stream>>>(hx16, row_ptr, colb, dinv, gcn_b, h);

    // GAT (gemm + fused logits -> fp16 g, then single-pass online softmax agg)
    k_gemm256<<<(NN + 31) / 32, 256, 0, stream>>>(h, gat_W, att_src, att_dst, g16, a_s, a_d);
    k_gat<<<NN / 4, 256, 0, stream>>>(g16, a_s, a_d, row_ptr, colb, gat_b, batch, pool, cnt_g);

    // output projection
    k_out<<<(NGRAPH * NOUT + 255) / 256, 256, 0, stream>>>(pool, cnt_g, out_W, out_b, out);
}